// Round 5
// baseline (317.001 us; speedup 1.0000x reference)
//
#include <hip/hip_runtime.h>

typedef __bf16 bf16;
typedef bf16 bf16x8 __attribute__((ext_vector_type(8)));
typedef bf16 bf16x4 __attribute__((ext_vector_type(4)));
typedef float f32x4 __attribute__((ext_vector_type(4)));
typedef float f32x16 __attribute__((ext_vector_type(16)));

#define MFMA16(a, b, c) __builtin_amdgcn_mfma_f32_16x16x32_bf16(a, b, c, 0, 0, 0)
#define MFMA32(a, b, c) __builtin_amdgcn_mfma_f32_32x32x16_bf16(a, b, c, 0, 0, 0)

__device__ __forceinline__ void async16(const bf16* g, bf16* l) {
    __builtin_amdgcn_global_load_lds(
        (const __attribute__((address_space(1))) unsigned int*)(g),
        (__attribute__((address_space(3))) unsigned int*)(l), 16, 0, 0);
}

__device__ __forceinline__ unsigned int pkbf(float a, float b) {
    union { bf16 h[2]; unsigned int u; } x;
    x.h[0] = (bf16)a; x.h[1] = (bf16)b;
    return x.u;
}

// ---------------- x -> bf16 ----------------
__global__ __launch_bounds__(256) void k_cvt_x(const float* __restrict__ x, bf16* __restrict__ o) {
    int i = (blockIdx.x * 256 + threadIdx.x) * 8;
    const float4* p = (const float4*)(x + i);
    float4 a = p[0], b = p[1];
    bf16x8 v;
    v[0] = (bf16)a.x; v[1] = (bf16)a.y; v[2] = (bf16)a.z; v[3] = (bf16)a.w;
    v[4] = (bf16)b.x; v[5] = (bf16)b.y; v[6] = (bf16)b.z; v[7] = (bf16)b.w;
    *(bf16x8*)(o + i) = v;
}

// ---------------- W [K][N] fp32 -> WT [N][K] bf16 ----------------
__global__ __launch_bounds__(256) void k_wt(const float* __restrict__ W, bf16* __restrict__ WT) {
    __shared__ bf16 lt[64][72];
    int t = threadIdx.x;
    int n0 = blockIdx.x * 64, k0 = blockIdx.y * 64;
#pragma unroll
    for (int j = 0; j < 4; j++) {
        int idx = t + 256 * j;
        int r = idx >> 4;
        int c4 = (idx & 15) << 2;
        float4 v = *(const float4*)&W[(size_t)(k0 + r) * 2048 + n0 + c4];
        lt[r][c4] = (bf16)v.x; lt[r][c4 + 1] = (bf16)v.y;
        lt[r][c4 + 2] = (bf16)v.z; lt[r][c4 + 3] = (bf16)v.w;
    }
    __syncthreads();
#pragma unroll
    for (int j = 0; j < 4; j++) {
        int idx = t + 256 * j;
        int n = idx >> 4;
        int k4 = (idx & 15) << 2;
        bf16x4 o;
        o[0] = lt[k4][n]; o[1] = lt[k4 + 1][n]; o[2] = lt[k4 + 2][n]; o[3] = lt[k4 + 3][n];
        *(bf16x4*)&WT[(size_t)(n0 + n) * 2048 + k0 + k4] = o;
    }
}

// ---------------- GEMM (m97 template): C[1024][2048] = A * Bt^T + bias, fp32 out ----
// linear LDS [128][32], global_load_lds width-16 staging, 2-barrier K-loop.
__global__ __launch_bounds__(256) void k_gemm(
    const bf16* __restrict__ A,
    const bf16* __restrict__ B0, const bf16* __restrict__ B1, const bf16* __restrict__ B2,
    const float* __restrict__ c0, const float* __restrict__ c1, const float* __restrict__ c2,
    float* __restrict__ D0, float* __restrict__ D1, float* __restrict__ D2) {
    const int N = 2048, K = 2048;
    const bf16* Bt = blockIdx.z == 0 ? B0 : (blockIdx.z == 1 ? B1 : B2);
    const float* bias = blockIdx.z == 0 ? c0 : (blockIdx.z == 1 ? c1 : c2);
    float* D = blockIdx.z == 0 ? D0 : (blockIdx.z == 1 ? D1 : D2);
    __shared__ bf16 Al[128 * 32];
    __shared__ bf16 Bl[128 * 32];
    int t = threadIdx.x;
    int lane = t & 63, w = t >> 6;
    int l15 = lane & 15, g = lane >> 4;
    int wr = w >> 1, wc = w & 1;
    int m0 = blockIdx.y * 128, n0 = blockIdx.x * 128;
    f32x4 acc[4][4] = {};
    int arow = t >> 2, acol = (t & 3) * 8;   // LDS elem t*8 = row t/4, col (t&3)*8
    for (int k0 = 0; k0 < K; k0 += 32) {
        async16(&A[(size_t)(m0 + arow) * K + k0 + acol], Al + t * 8);
        async16(&A[(size_t)(m0 + 64 + arow) * K + k0 + acol], Al + 2048 + t * 8);
        async16(&Bt[(size_t)(n0 + arow) * K + k0 + acol], Bl + t * 8);
        async16(&Bt[(size_t)(n0 + 64 + arow) * K + k0 + acol], Bl + 2048 + t * 8);
        __syncthreads();   // drains vmcnt -> tiles ready
        bf16x8 af[4], bfr[4];
#pragma unroll
        for (int i = 0; i < 4; i++) af[i] = *(const bf16x8*)&Al[(wr * 64 + i * 16 + l15) * 32 + g * 8];
#pragma unroll
        for (int i = 0; i < 4; i++) bfr[i] = *(const bf16x8*)&Bl[(wc * 64 + i * 16 + l15) * 32 + g * 8];
#pragma unroll
        for (int mi = 0; mi < 4; mi++)
#pragma unroll
            for (int ni = 0; ni < 4; ni++)
                acc[mi][ni] = MFMA16(af[mi], bfr[ni], acc[mi][ni]);
        __syncthreads();   // all reads done before next stage overwrites
    }
#pragma unroll
    for (int mi = 0; mi < 4; mi++) {
#pragma unroll
        for (int ni = 0; ni < 4; ni++) {
            int n = n0 + wc * 64 + ni * 16 + l15;
            float bv = bias[n];
#pragma unroll
            for (int r = 0; r < 4; r++) {
                int m = m0 + wr * 64 + mi * 16 + g * 4 + r;
                D[(size_t)m * N + n] = acc[mi][ni][r] + bv;
            }
        }
    }
}

// ---------------- rmsnorm + rope (Q scale folded with log2e) ----------------
__global__ __launch_bounds__(256) void k_normrope(
    const float* __restrict__ qraw, const float* __restrict__ kraw,
    const float* __restrict__ gq, const float* __restrict__ gk,
    const float* __restrict__ theta,
    bf16* __restrict__ Qb, bf16* __restrict__ Kb) {
    int l = blockIdx.x, t = threadIdx.x;
    int lane = t & 63, w = t >> 6;
    int c = t * 8;
    float qv[8], kv[8];
    const float4* qp = (const float4*)(qraw + (size_t)l * 2048 + c);
    const float4* kp = (const float4*)(kraw + (size_t)l * 2048 + c);
    float4 a;
    a = qp[0]; qv[0] = a.x; qv[1] = a.y; qv[2] = a.z; qv[3] = a.w;
    a = qp[1]; qv[4] = a.x; qv[5] = a.y; qv[6] = a.z; qv[7] = a.w;
    a = kp[0]; kv[0] = a.x; kv[1] = a.y; kv[2] = a.z; kv[3] = a.w;
    a = kp[1]; kv[4] = a.x; kv[5] = a.y; kv[6] = a.z; kv[7] = a.w;
    float ssq = 0.f, ssk = 0.f;
#pragma unroll
    for (int j = 0; j < 8; j++) { ssq += qv[j] * qv[j]; ssk += kv[j] * kv[j]; }
#pragma unroll
    for (int m = 1; m < 64; m <<= 1) { ssq += __shfl_xor(ssq, m); ssk += __shfl_xor(ssk, m); }
    __shared__ float rq[4], rk[4];
    if (lane == 0) { rq[w] = ssq; rk[w] = ssk; }
    __syncthreads();
    ssq = rq[0] + rq[1] + rq[2] + rq[3];
    ssk = rk[0] + rk[1] + rk[2] + rk[3];
    float iq = rsqrtf(ssq * (1.0f / 2048.0f) + 1e-6f);
    float ik = rsqrtf(ssk * (1.0f / 2048.0f) + 1e-6f);
#pragma unroll
    for (int j = 0; j < 8; j++) { qv[j] *= iq * gq[c + j]; kv[j] *= ik * gk[c + j]; }
    int h = c >> 7, dd = c & 127;
    bf16x8 qo, ko;
    // log2(e) / sqrt(128): softmax runs in base-2
    const float SC = 1.4426950408889634f / 11.313708498984761f;
#pragma unroll
    for (int p = 0; p < 4; p++) {
        float th = theta[l * 64 + (dd >> 1) + p];
        float sn, cs;
        __sincosf(th, &sn, &cs);
        float qr = qv[2 * p] * cs - qv[2 * p + 1] * sn;
        float qi = qv[2 * p] * sn + qv[2 * p + 1] * cs;
        float kr = kv[2 * p] * cs - kv[2 * p + 1] * sn;
        float ki = kv[2 * p] * sn + kv[2 * p + 1] * cs;
        qo[2 * p] = (bf16)(qr * SC); qo[2 * p + 1] = (bf16)(qi * SC);
        ko[2 * p] = (bf16)kr;        ko[2 * p + 1] = (bf16)ki;
    }
    *(bf16x8*)&Qb[(size_t)h * 131072 + (size_t)l * 128 + dd] = qo;
    *(bf16x8*)&Kb[(size_t)h * 1048576 + (size_t)l * 128 + dd] = ko;
}

// ---------------- V transpose: [s][n*128+d] fp32 -> Vt[n][d][s] bf16 ----------------
__global__ __launch_bounds__(256) void k_vtrans(
    const float* __restrict__ vraw, const float* __restrict__ cache_v, bf16* __restrict__ Vt) {
    int st = blockIdx.x;
    int n = blockIdx.y;
    int s0 = st * 64;
    const float* src = (s0 < 1024) ? (vraw + (size_t)s0 * 2048) : (cache_v + (size_t)s0 * 2048);
    __shared__ bf16 lt[64][132];
    int t = threadIdx.x;
#pragma unroll
    for (int j = 0; j < 8; j++) {
        int idx = t + 256 * j;
        int i = idx >> 5;
        int d4 = (idx & 31) << 2;
        float4 v = *(const float4*)&src[(size_t)i * 2048 + n * 128 + d4];
        lt[i][d4] = (bf16)v.x; lt[i][d4 + 1] = (bf16)v.y;
        lt[i][d4 + 2] = (bf16)v.z; lt[i][d4 + 3] = (bf16)v.w;
    }
    __syncthreads();
    int d = t >> 1, sh = (t & 1) << 5;
    bf16* dst = Vt + (size_t)n * 1048576 + (size_t)d * 8192 + s0 + sh;
#pragma unroll
    for (int q = 0; q < 4; q++) {
        bf16x8 o;
#pragma unroll
        for (int e = 0; e < 8; e++) o[e] = lt[sh + q * 8 + e][d];
        *(bf16x8*)&dst[q * 8] = o;
    }
}

// ---------------- cache_k repack: [s][n][d] fp32 -> Kb[n][s][d] bf16 (s >= 1024) ----------------
__global__ __launch_bounds__(256) void k_repack_k(const float* __restrict__ cache_k, bf16* __restrict__ Kb) {
    int s = 1024 + blockIdx.x;
    int t = threadIdx.x;
    int e = t * 8;
    int n = e >> 7, d = e & 127;
    const float4* p = (const float4*)&cache_k[(size_t)s * 2048 + e];
    float4 a = p[0], b = p[1];
    bf16x8 v;
    v[0] = (bf16)a.x; v[1] = (bf16)a.y; v[2] = (bf16)a.z; v[3] = (bf16)a.w;
    v[4] = (bf16)b.x; v[5] = (bf16)b.y; v[6] = (bf16)b.z; v[7] = (bf16)b.w;
    *(bf16x8*)&Kb[(size_t)n * 1048576 + (size_t)s * 128 + d] = v;
}

// ---------------- flash attention: swapped 32x32 MFMA, in-register softmax ----------------
// flat grid 768 = 256 CU x 3 blocks (launch_bounds 3: all co-resident).
// XCD-aware work remap: the 8 qblks sharing an (h,z) K/V slice map to blocks
// with equal b&7 -> same XCD under round-robin dispatch -> slice stays in that
// XCD's L2 (0.7 MB << 4 MB).
// Staging: reg-staged T14 split (loads for it+1 issued before compute of it).
__global__ __launch_bounds__(256, 3) void k_flash(
    const bf16* __restrict__ Qb, const bf16* __restrict__ Kb, const bf16* __restrict__ Vt,
    float* __restrict__ Opart, float2* __restrict__ MLpart) {
    int b = blockIdx.x;
    int cx = b & 7, jj = b >> 3;           // cx = XCD (heuristic), jj = 0..95
    int p = cx + 8 * (jj >> 3);            // (h,z) pair 0..95
    int qb = jj & 7;
    int h = p & 15, z = p >> 4;
    int q0 = qb * 128;
    int t = threadIdx.x;
    int lane = t & 63, wq = t >> 6;
    int l31 = lane & 31, hi = lane >> 5;
    __shared__ bf16 Kl[64 * 128];   // [k][d], 16B slots XOR-swizzled by row&7
    __shared__ bf16 Vl[128 * 64];   // [d][s], 16B slots XOR-swizzled by d&7
    const bf16* Kh = Kb + (size_t)h * 1048576;
    const bf16* Vh = Vt + (size_t)h * 1048576;
    int q = q0 + wq * 32 + l31;
    bf16x8 qf[8];
#pragma unroll
    for (int db = 0; db < 8; db++)
        qf[db] = *(const bf16x8*)&Qb[(size_t)h * 131072 + (size_t)q * 128 + db * 16 + hi * 8];
    f32x16 o[4] = {};
    float mm = -1e30f, ll = 0.f;
    // staging addressing: linear global, swizzled LDS write (per-lane ds_write scatter)
    int krow = t >> 4;                                        // 0..15 (+16j)
    int kcol = (t & 15) * 8;
    int kdst = krow * 128 + (((t & 15) ^ (krow & 7)) * 8);
    int vrow = t >> 3;                                        // 0..31 (+32j)
    int vcol = (t & 7) * 8;
    int vdst = vrow * 64 + (((t & 7) ^ (vrow & 7)) * 8);
    int swr = (l31 & 7) << 3;
    int it0 = (128 * z) / 6, it1 = (128 * (z + 1)) / 6;
    bf16x8 kst[4], vst[4];
    {
        int s0 = it0 * 64;
#pragma unroll
        for (int j = 0; j < 4; j++)
            kst[j] = *(const bf16x8*)&Kh[(size_t)(s0 + krow + 16 * j) * 128 + kcol];
#pragma unroll
        for (int j = 0; j < 4; j++)
            vst[j] = *(const bf16x8*)&Vh[(size_t)(vrow + 32 * j) * 8192 + s0 + vcol];
    }
    for (int it = it0; it < it1; ++it) {
        __syncthreads();   // previous iteration's LDS reads complete
#pragma unroll
        for (int j = 0; j < 4; j++) *(bf16x8*)&Kl[kdst + j * 2048] = kst[j];
#pragma unroll
        for (int j = 0; j < 4; j++) *(bf16x8*)&Vl[vdst + j * 2048] = vst[j];
        __syncthreads();   // LDS tile ready
        if (it + 1 < it1) {
            int s1 = (it + 1) * 64;
#pragma unroll
            for (int j = 0; j < 4; j++)
                kst[j] = *(const bf16x8*)&Kh[(size_t)(s1 + krow + 16 * j) * 128 + kcol];
#pragma unroll
            for (int j = 0; j < 4; j++)
                vst[j] = *(const bf16x8*)&Vh[(size_t)(vrow + 32 * j) * 8192 + s1 + vcol];
        }
        // QK^T swapped: sA = K[0:32] x Q^T, sB = K[32:64] x Q^T
        f32x16 sA = {}, sB = {};
#pragma unroll
        for (int db = 0; db < 8; db++) {
            int doff = (db * 16 + hi * 8) ^ swr;
            bf16x8 ka = *(const bf16x8*)&Kl[l31 * 128 + doff];
            bf16x8 kb = *(const bf16x8*)&Kl[(32 + l31) * 128 + doff];
            sA = MFMA32(ka, qf[db], sA);
            sB = MFMA32(kb, qf[db], sB);
        }
        // in-register softmax (base-2), defer-max
        float tm = -1e30f;
#pragma unroll
        for (int r = 0; r < 16; r++) { tm = fmaxf(tm, sA[r]); tm = fmaxf(tm, sB[r]); }
        tm = fmaxf(tm, __shfl_xor(tm, 32));
        if (__any(tm > mm + 11.5416f)) {
            float mn = fmaxf(mm, tm);
            float al = exp2f(mm - mn);
#pragma unroll
            for (int dt = 0; dt < 4; dt++)
#pragma unroll
                for (int r = 0; r < 16; r++) o[dt][r] *= al;
            ll *= al; mm = mn;
        }
        float ps = 0.f;
#pragma unroll
        for (int r = 0; r < 16; r++) { sA[r] = exp2f(sA[r] - mm); ps += sA[r]; }
#pragma unroll
        for (int r = 0; r < 16; r++) { sB[r] = exp2f(sB[r] - mm); ps += sB[r]; }
        ll += ps + __shfl_xor(ps, 32);
        // pack P to bf16 words: w[2*qd+j] = regs 4qd+2j, 4qd+2j+1
        unsigned int w0[8], w1[8];
#pragma unroll
        for (int qd = 0; qd < 4; qd++) {
            w0[qd * 2]     = pkbf(sA[qd * 4], sA[qd * 4 + 1]);
            w0[qd * 2 + 1] = pkbf(sA[qd * 4 + 2], sA[qd * 4 + 3]);
            w1[qd * 2]     = pkbf(sB[qd * 4], sB[qd * 4 + 1]);
            w1[qd * 2 + 1] = pkbf(sB[qd * 4 + 2], sB[qd * 4 + 3]);
        }
        // PV: O^T += V^T x P^T, 4 k-steps of 16
#pragma unroll
        for (int ks = 0; ks < 4; ks++) {
            const int a4 = (ks & 1) * 4;
            unsigned int oo0, oo1, ss0, ss1;
            if ((ks >> 1) == 0) {
                oo0 = hi ? w0[a4 + 2] : w0[a4];
                oo1 = hi ? w0[a4 + 3] : w0[a4 + 1];
                ss0 = hi ? w0[a4] : w0[a4 + 2];
                ss1 = hi ? w0[a4 + 1] : w0[a4 + 3];
            } else {
                oo0 = hi ? w1[a4 + 2] : w1[a4];
                oo1 = hi ? w1[a4 + 3] : w1[a4 + 1];
                ss0 = hi ? w1[a4] : w1[a4 + 2];
                ss1 = hi ? w1[a4 + 1] : w1[a4 + 3];
            }
            unsigned int x0 = (unsigned int)__shfl_xor((int)ss0, 32);
            unsigned int x1 = (unsigned int)__shfl_xor((int)ss1, 32);
            union { unsigned int w[4]; bf16x8 v; } fr;
            fr.w[0] = hi ? x0 : oo0;
            fr.w[1] = hi ? x1 : oo1;
            fr.w[2] = hi ? oo0 : x0;
            fr.w[3] = hi ? oo1 : x1;
#pragma unroll
            for (int dt = 0; dt < 4; dt++) {
                int e = (dt * 32 + l31) * 64 + ((ks * 16 + hi * 8) ^ swr);
                bf16x8 vf = *(const bf16x8*)&Vl[e];
                o[dt] = MFMA32(vf, fr.v, o[dt]);
            }
        }
    }
    size_t obase = ((size_t)(z * 16 + h) * 1024 + q) * 128;
#pragma unroll
    for (int dt = 0; dt < 4; dt++)
#pragma unroll
        for (int r = 0; r < 16; r++) {
            int d = dt * 32 + (r & 3) + 8 * (r >> 2) + 4 * hi;
            Opart[obase + d] = o[dt][r];
        }
    if (hi == 0) MLpart[(size_t)(z * 16 + h) * 1024 + q] = make_float2(mm, ll);
}

// ---------------- combine 6 partials -> Ob bf16 [q][h*128+d] ----------------
__global__ __launch_bounds__(256) void k_combine(
    const float* __restrict__ Opart, const float2* __restrict__ MLpart,
    bf16* __restrict__ Ob) {
    int q = blockIdx.x, t = threadIdx.x;
    int h = t >> 4, d0 = (t & 15) * 8;
    float m[6], l[6];
#pragma unroll
    for (int z = 0; z < 6; z++) {
        float2 v = MLpart[(size_t)(z * 16 + h) * 1024 + q];
        m[z] = v.x; l[z] = v.y;
    }
    float M = -1e30f;
#pragma unroll
    for (int z = 0; z < 6; z++) M = fmaxf(M, m[z]);
    float e[6], den = 0.f;
#pragma unroll
    for (int z = 0; z < 6; z++) { e[z] = exp2f(m[z] - M); den += e[z] * l[z]; }
    float inv = 1.0f / den;
    float acc[8] = {};
#pragma unroll
    for (int z = 0; z < 6; z++) {
        const float4* p = (const float4*)&Opart[((size_t)(z * 16 + h) * 1024 + q) * 128 + d0];
        float4 a = p[0], b = p[1];
        float s = e[z] * inv;
        acc[0] += a.x * s; acc[1] += a.y * s; acc[2] += a.z * s; acc[3] += a.w * s;
        acc[4] += b.x * s; acc[5] += b.y * s; acc[6] += b.z * s; acc[7] += b.w * s;
    }
    bf16x8 ov;
#pragma unroll
    for (int j = 0; j < 8; j++) ov[j] = (bf16)acc[j];
    *(bf16x8*)&Ob[(size_t)q * 2048 + h * 128 + d0] = ov;
}

extern "C" void kernel_launch(void* const* d_in, const int* in_sizes, int n_in,
                              void* d_out, int out_size, void* d_ws, size_t ws_size,
                              hipStream_t stream) {
    const float* x       = (const float*)d_in[0];
    const float* cache_k = (const float*)d_in[1];
    const float* cache_v = (const float*)d_in[2];
    const float* theta   = (const float*)d_in[5];
    const float* Wq = (const float*)d_in[6];
    const float* bq = (const float*)d_in[7];
    const float* Wk = (const float*)d_in[8];
    const float* bk = (const float*)d_in[9];
    const float* Wv = (const float*)d_in[10];
    const float* bv = (const float*)d_in[11];
    const float* Wo = (const float*)d_in[12];
    const float* bo = (const float*)d_in[13];
    const float* gq = (const float*)d_in[14];
    const float* gk = (const float*)d_in[15];
    float* out = (float*)d_out;

    // ws layout (132 MB). WoT placed before WqT so WqT..vraw (48MB) is a
    // contiguous dead region at flash time -> Opart overlay.
    bf16* xbf = (bf16*)d_ws;                 // 4 MB; dead after QKV gemm -> MLpart
    bf16* WoT = xbf + 2097152;               // 8 MB (alive until final gemm)
    bf16* WqT = WoT + 4194304;               // 8 MB
    bf16* WkT = WqT + 4194304;
    bf16* WvT = WkT + 4194304;
    float* qraw = (float*)(WvT + 4194304);   // 8 MB each
    float* kraw = qraw + 2097152;
    float* vraw = kraw + 2097152;
    bf16* Qb = (bf16*)(vraw + 2097152);      // [16][1024][128]
    bf16* Kb = Qb + 2097152;                 // [16][8192][128]
    bf16* Vt = Kb + 16777216;                // [16][128][8192]
    bf16* Ob = Vt + 16777216;                // [1024][2048]

    float* Opart = (float*)WqT;              // [6][16][1024][128] fp32 = 48 MB
    float2* MLpart = (float2*)xbf;           // [6][16][1024] float2 = 768 KB

    k_cvt_x<<<1024, 256, 0, stream>>>(x, xbf);
    k_wt<<<dim3(32, 32), 256, 0, stream>>>(Wq, WqT);
    k_wt<<<dim3(32, 32), 256, 0, stream>>>(Wk, WkT);
    k_wt<<<dim3(32, 32), 256, 0, stream>>>(Wv, WvT);
    k_wt<<<dim3(32, 32), 256, 0, stream>>>(Wo, WoT);
    k_gemm<<<dim3(16, 8, 3), 256, 0, stream>>>(xbf, WqT, WkT, WvT, bq, bk, bv, qraw, kraw, vraw);
    k_normrope<<<1024, 256, 0, stream>>>(qraw, kraw, gq, gk, theta, Qb, Kb);
    k_vtrans<<<dim3(128, 16), 256, 0, stream>>>(vraw, cache_v, Vt);
    k_repack_k<<<7168, 256, 0, stream>>>(cache_k, Kb);
    k_flash<<<768, 256, 0, stream>>>(Qb, Kb, Vt, Opart, MLpart);
    k_combine<<<1024, 256, 0, stream>>>(Opart, MLpart, Ob);
    k_gemm<<<dim3(16, 8, 1), 256, 0, stream>>>(Ob, WoT, WoT, WoT, bo, bo, bo, out, out, out);
}

// Round 6
// 314.052 us; speedup vs baseline: 1.0094x; 1.0094x over previous
//
#include <hip/hip_runtime.h>

typedef __bf16 bf16;
typedef bf16 bf16x8 __attribute__((ext_vector_type(8)));
typedef bf16 bf16x4 __attribute__((ext_vector_type(4)));
typedef float f32x4 __attribute__((ext_vector_type(4)));
typedef float f32x16 __attribute__((ext_vector_type(16)));

#define MFMA16(a, b, c) __builtin_amdgcn_mfma_f32_16x16x32_bf16(a, b, c, 0, 0, 0)
#define MFMA32(a, b, c) __builtin_amdgcn_mfma_f32_32x32x16_bf16(a, b, c, 0, 0, 0)

__device__ __forceinline__ void async16(const bf16* g, bf16* l) {
    __builtin_amdgcn_global_load_lds(
        (const __attribute__((address_space(1))) unsigned int*)(g),
        (__attribute__((address_space(3))) unsigned int*)(l), 16, 0, 0);
}

__device__ __forceinline__ unsigned int pkbf(float a, float b) {
    union { bf16 h[2]; unsigned int u; } x;
    x.h[0] = (bf16)a; x.h[1] = (bf16)b;
    return x.u;
}

// ---------------- x -> bf16 ----------------
__global__ __launch_bounds__(256) void k_cvt_x(const float* __restrict__ x, bf16* __restrict__ o) {
    int i = (blockIdx.x * 256 + threadIdx.x) * 8;
    const float4* p = (const float4*)(x + i);
    float4 a = p[0], b = p[1];
    bf16x8 v;
    v[0] = (bf16)a.x; v[1] = (bf16)a.y; v[2] = (bf16)a.z; v[3] = (bf16)a.w;
    v[4] = (bf16)b.x; v[5] = (bf16)b.y; v[6] = (bf16)b.z; v[7] = (bf16)b.w;
    *(bf16x8*)(o + i) = v;
}

// ---------------- W [K][N] fp32 -> WT [N][K] bf16 ----------------
__global__ __launch_bounds__(256) void k_wt(const float* __restrict__ W, bf16* __restrict__ WT) {
    __shared__ bf16 lt[64][72];
    int t = threadIdx.x;
    int n0 = blockIdx.x * 64, k0 = blockIdx.y * 64;
#pragma unroll
    for (int j = 0; j < 4; j++) {
        int idx = t + 256 * j;
        int r = idx >> 4;
        int c4 = (idx & 15) << 2;
        float4 v = *(const float4*)&W[(size_t)(k0 + r) * 2048 + n0 + c4];
        lt[r][c4] = (bf16)v.x; lt[r][c4 + 1] = (bf16)v.y;
        lt[r][c4 + 2] = (bf16)v.z; lt[r][c4 + 3] = (bf16)v.w;
    }
    __syncthreads();
#pragma unroll
    for (int j = 0; j < 4; j++) {
        int idx = t + 256 * j;
        int n = idx >> 4;
        int k4 = (idx & 15) << 2;
        bf16x4 o;
        o[0] = lt[k4][n]; o[1] = lt[k4 + 1][n]; o[2] = lt[k4 + 2][n]; o[3] = lt[k4 + 3][n];
        *(bf16x4*)&WT[(size_t)(n0 + n) * 2048 + k0 + k4] = o;
    }
}

// ---------------- GEMM (m97 template): C[1024][2048] = A * Bt^T + bias, fp32 out ----
__global__ __launch_bounds__(256) void k_gemm(
    const bf16* __restrict__ A,
    const bf16* __restrict__ B0, const bf16* __restrict__ B1, const bf16* __restrict__ B2,
    const float* __restrict__ c0, const float* __restrict__ c1, const float* __restrict__ c2,
    float* __restrict__ D0, float* __restrict__ D1, float* __restrict__ D2) {
    const int N = 2048, K = 2048;
    const bf16* Bt = blockIdx.z == 0 ? B0 : (blockIdx.z == 1 ? B1 : B2);
    const float* bias = blockIdx.z == 0 ? c0 : (blockIdx.z == 1 ? c1 : c2);
    float* D = blockIdx.z == 0 ? D0 : (blockIdx.z == 1 ? D1 : D2);
    __shared__ bf16 Al[128 * 32];
    __shared__ bf16 Bl[128 * 32];
    int t = threadIdx.x;
    int lane = t & 63, w = t >> 6;
    int l15 = lane & 15, g = lane >> 4;
    int wr = w >> 1, wc = w & 1;
    int m0 = blockIdx.y * 128, n0 = blockIdx.x * 128;
    f32x4 acc[4][4] = {};
    int arow = t >> 2, acol = (t & 3) * 8;
    for (int k0 = 0; k0 < K; k0 += 32) {
        async16(&A[(size_t)(m0 + arow) * K + k0 + acol], Al + t * 8);
        async16(&A[(size_t)(m0 + 64 + arow) * K + k0 + acol], Al + 2048 + t * 8);
        async16(&Bt[(size_t)(n0 + arow) * K + k0 + acol], Bl + t * 8);
        async16(&Bt[(size_t)(n0 + 64 + arow) * K + k0 + acol], Bl + 2048 + t * 8);
        __syncthreads();
        bf16x8 af[4], bfr[4];
#pragma unroll
        for (int i = 0; i < 4; i++) af[i] = *(const bf16x8*)&Al[(wr * 64 + i * 16 + l15) * 32 + g * 8];
#pragma unroll
        for (int i = 0; i < 4; i++) bfr[i] = *(const bf16x8*)&Bl[(wc * 64 + i * 16 + l15) * 32 + g * 8];
#pragma unroll
        for (int mi = 0; mi < 4; mi++)
#pragma unroll
            for (int ni = 0; ni < 4; ni++)
                acc[mi][ni] = MFMA16(af[mi], bfr[ni], acc[mi][ni]);
        __syncthreads();
    }
#pragma unroll
    for (int mi = 0; mi < 4; mi++) {
#pragma unroll
        for (int ni = 0; ni < 4; ni++) {
            int n = n0 + wc * 64 + ni * 16 + l15;
            float bv = bias[n];
#pragma unroll
            for (int r = 0; r < 4; r++) {
                int m = m0 + wr * 64 + mi * 16 + g * 4 + r;
                D[(size_t)m * N + n] = acc[mi][ni][r] + bv;
            }
        }
    }
}

// ---------------- rmsnorm + rope (Q scale folded with log2e) ----------------
__global__ __launch_bounds__(256) void k_normrope(
    const float* __restrict__ qraw, const float* __restrict__ kraw,
    const float* __restrict__ gq, const float* __restrict__ gk,
    const float* __restrict__ theta,
    bf16* __restrict__ Qb, bf16* __restrict__ Kb) {
    int l = blockIdx.x, t = threadIdx.x;
    int lane = t & 63, w = t >> 6;
    int c = t * 8;
    float qv[8], kv[8];
    const float4* qp = (const float4*)(qraw + (size_t)l * 2048 + c);
    const float4* kp = (const float4*)(kraw + (size_t)l * 2048 + c);
    float4 a;
    a = qp[0]; qv[0] = a.x; qv[1] = a.y; qv[2] = a.z; qv[3] = a.w;
    a = qp[1]; qv[4] = a.x; qv[5] = a.y; qv[6] = a.z; qv[7] = a.w;
    a = kp[0]; kv[0] = a.x; kv[1] = a.y; kv[2] = a.z; kv[3] = a.w;
    a = kp[1]; kv[4] = a.x; kv[5] = a.y; kv[6] = a.z; kv[7] = a.w;
    float ssq = 0.f, ssk = 0.f;
#pragma unroll
    for (int j = 0; j < 8; j++) { ssq += qv[j] * qv[j]; ssk += kv[j] * kv[j]; }
#pragma unroll
    for (int m = 1; m < 64; m <<= 1) { ssq += __shfl_xor(ssq, m); ssk += __shfl_xor(ssk, m); }
    __shared__ float rq[4], rk[4];
    if (lane == 0) { rq[w] = ssq; rk[w] = ssk; }
    __syncthreads();
    ssq = rq[0] + rq[1] + rq[2] + rq[3];
    ssk = rk[0] + rk[1] + rk[2] + rk[3];
    float iq = rsqrtf(ssq * (1.0f / 2048.0f) + 1e-6f);
    float ik = rsqrtf(ssk * (1.0f / 2048.0f) + 1e-6f);
#pragma unroll
    for (int j = 0; j < 8; j++) { qv[j] *= iq * gq[c + j]; kv[j] *= ik * gk[c + j]; }
    int h = c >> 7, dd = c & 127;
    bf16x8 qo, ko;
    // log2(e) / sqrt(128): softmax runs in base-2
    const float SC = 1.4426950408889634f / 11.313708498984761f;
#pragma unroll
    for (int p = 0; p < 4; p++) {
        float th = theta[l * 64 + (dd >> 1) + p];
        float sn, cs;
        __sincosf(th, &sn, &cs);
        float qr = qv[2 * p] * cs - qv[2 * p + 1] * sn;
        float qi = qv[2 * p] * sn + qv[2 * p + 1] * cs;
        float kr = kv[2 * p] * cs - kv[2 * p + 1] * sn;
        float ki = kv[2 * p] * sn + kv[2 * p + 1] * cs;
        qo[2 * p] = (bf16)(qr * SC); qo[2 * p + 1] = (bf16)(qi * SC);
        ko[2 * p] = (bf16)kr;        ko[2 * p + 1] = (bf16)ki;
    }
    *(bf16x8*)&Qb[(size_t)h * 131072 + (size_t)l * 128 + dd] = qo;
    *(bf16x8*)&Kb[(size_t)h * 1048576 + (size_t)l * 128 + dd] = ko;
}

// ---------------- V transpose: [s][n*128+d] fp32 -> Vt[n][d][s] bf16 ----------------
__global__ __launch_bounds__(256) void k_vtrans(
    const float* __restrict__ vraw, const float* __restrict__ cache_v, bf16* __restrict__ Vt) {
    int st = blockIdx.x;
    int n = blockIdx.y;
    int s0 = st * 64;
    const float* src = (s0 < 1024) ? (vraw + (size_t)s0 * 2048) : (cache_v + (size_t)s0 * 2048);
    __shared__ bf16 lt[64][132];
    int t = threadIdx.x;
#pragma unroll
    for (int j = 0; j < 8; j++) {
        int idx = t + 256 * j;
        int i = idx >> 5;
        int d4 = (idx & 31) << 2;
        float4 v = *(const float4*)&src[(size_t)i * 2048 + n * 128 + d4];
        lt[i][d4] = (bf16)v.x; lt[i][d4 + 1] = (bf16)v.y;
        lt[i][d4 + 2] = (bf16)v.z; lt[i][d4 + 3] = (bf16)v.w;
    }
    __syncthreads();
    int d = t >> 1, sh = (t & 1) << 5;
    bf16* dst = Vt + (size_t)n * 1048576 + (size_t)d * 8192 + s0 + sh;
#pragma unroll
    for (int q = 0; q < 4; q++) {
        bf16x8 o;
#pragma unroll
        for (int e = 0; e < 8; e++) o[e] = lt[sh + q * 8 + e][d];
        *(bf16x8*)&dst[q * 8] = o;
    }
}

// ---------------- cache_k repack: [s][n][d] fp32 -> Kb[n][s][d] bf16 (s >= 1024) ----------------
__global__ __launch_bounds__(256) void k_repack_k(const float* __restrict__ cache_k, bf16* __restrict__ Kb) {
    int s = 1024 + blockIdx.x;
    int t = threadIdx.x;
    int e = t * 8;
    int n = e >> 7, d = e & 127;
    const float4* p = (const float4*)&cache_k[(size_t)s * 2048 + e];
    float4 a = p[0], b = p[1];
    bf16x8 v;
    v[0] = (bf16)a.x; v[1] = (bf16)a.y; v[2] = (bf16)a.z; v[3] = (bf16)a.w;
    v[4] = (bf16)b.x; v[5] = (bf16)b.y; v[6] = (bf16)b.z; v[7] = (bf16)b.w;
    *(bf16x8*)&Kb[(size_t)n * 1048576 + (size_t)s * 128 + d] = v;
}

// ---------------- flash attention: swapped 32x32 MFMA, in-register softmax ----------------
// flat grid 768 = 256 CU x 3 blocks; XCD-aware remap (b&7 = XCD); reg-staged T14.
// Opart layout is PERMUTED per q-row: p = hi*64 + dt*16 + c*4 + j holds O element
// d = dt*32 + 8c + 4hi + j. Each lane stores its 64 floats as 16 contiguous
// float4 (256B region = 4 full cache lines per lane) -> no partial-line writes.
__global__ __launch_bounds__(256, 3) void k_flash(
    const bf16* __restrict__ Qb, const bf16* __restrict__ Kb, const bf16* __restrict__ Vt,
    float* __restrict__ Opart, float2* __restrict__ MLpart) {
    int b = blockIdx.x;
    int cx = b & 7, jj = b >> 3;           // cx = XCD (heuristic), jj = 0..95
    int p = cx + 8 * (jj >> 3);            // (h,z) pair 0..95
    int qb = jj & 7;
    int h = p & 15, z = p >> 4;
    int q0 = qb * 128;
    int t = threadIdx.x;
    int lane = t & 63, wq = t >> 6;
    int l31 = lane & 31, hi = lane >> 5;
    __shared__ bf16 Kl[64 * 128];   // [k][d], 16B slots XOR-swizzled by row&7
    __shared__ bf16 Vl[128 * 64];   // [d][s], 16B slots XOR-swizzled by d&7
    const bf16* Kh = Kb + (size_t)h * 1048576;
    const bf16* Vh = Vt + (size_t)h * 1048576;
    int q = q0 + wq * 32 + l31;
    bf16x8 qf[8];
#pragma unroll
    for (int db = 0; db < 8; db++)
        qf[db] = *(const bf16x8*)&Qb[(size_t)h * 131072 + (size_t)q * 128 + db * 16 + hi * 8];
    f32x16 o[4] = {};
    float mm = -1e30f, ll = 0.f;
    int krow = t >> 4;
    int kcol = (t & 15) * 8;
    int kdst = krow * 128 + (((t & 15) ^ (krow & 7)) * 8);
    int vrow = t >> 3;
    int vcol = (t & 7) * 8;
    int vdst = vrow * 64 + (((t & 7) ^ (vrow & 7)) * 8);
    int swr = (l31 & 7) << 3;
    int it0 = (128 * z) / 6, it1 = (128 * (z + 1)) / 6;
    bf16x8 kst[4], vst[4];
    {
        int s0 = it0 * 64;
#pragma unroll
        for (int j = 0; j < 4; j++)
            kst[j] = *(const bf16x8*)&Kh[(size_t)(s0 + krow + 16 * j) * 128 + kcol];
#pragma unroll
        for (int j = 0; j < 4; j++)
            vst[j] = *(const bf16x8*)&Vh[(size_t)(vrow + 32 * j) * 8192 + s0 + vcol];
    }
    for (int it = it0; it < it1; ++it) {
        __syncthreads();   // previous iteration's LDS reads complete
#pragma unroll
        for (int j = 0; j < 4; j++) *(bf16x8*)&Kl[kdst + j * 2048] = kst[j];
#pragma unroll
        for (int j = 0; j < 4; j++) *(bf16x8*)&Vl[vdst + j * 2048] = vst[j];
        __syncthreads();   // LDS tile ready
        if (it + 1 < it1) {
            int s1 = (it + 1) * 64;
#pragma unroll
            for (int j = 0; j < 4; j++)
                kst[j] = *(const bf16x8*)&Kh[(size_t)(s1 + krow + 16 * j) * 128 + kcol];
#pragma unroll
            for (int j = 0; j < 4; j++)
                vst[j] = *(const bf16x8*)&Vh[(size_t)(vrow + 32 * j) * 8192 + s1 + vcol];
        }
        // QK^T swapped: sA = K[0:32] x Q^T, sB = K[32:64] x Q^T
        f32x16 sA = {}, sB = {};
#pragma unroll
        for (int db = 0; db < 8; db++) {
            int doff = (db * 16 + hi * 8) ^ swr;
            bf16x8 ka = *(const bf16x8*)&Kl[l31 * 128 + doff];
            bf16x8 kb = *(const bf16x8*)&Kl[(32 + l31) * 128 + doff];
            sA = MFMA32(ka, qf[db], sA);
            sB = MFMA32(kb, qf[db], sB);
        }
        // in-register softmax (base-2), defer-max
        float tm = -1e30f;
#pragma unroll
        for (int r = 0; r < 16; r++) { tm = fmaxf(tm, sA[r]); tm = fmaxf(tm, sB[r]); }
        tm = fmaxf(tm, __shfl_xor(tm, 32));
        if (__any(tm > mm + 11.5416f)) {
            float mn = fmaxf(mm, tm);
            float al = exp2f(mm - mn);
#pragma unroll
            for (int dt = 0; dt < 4; dt++)
#pragma unroll
                for (int r = 0; r < 16; r++) o[dt][r] *= al;
            ll *= al; mm = mn;
        }
        float ps = 0.f;
#pragma unroll
        for (int r = 0; r < 16; r++) { sA[r] = exp2f(sA[r] - mm); ps += sA[r]; }
#pragma unroll
        for (int r = 0; r < 16; r++) { sB[r] = exp2f(sB[r] - mm); ps += sB[r]; }
        ll += ps + __shfl_xor(ps, 32);
        // pack P to bf16 words: w[2*qd+j] = regs 4qd+2j, 4qd+2j+1
        unsigned int w0[8], w1[8];
#pragma unroll
        for (int qd = 0; qd < 4; qd++) {
            w0[qd * 2]     = pkbf(sA[qd * 4], sA[qd * 4 + 1]);
            w0[qd * 2 + 1] = pkbf(sA[qd * 4 + 2], sA[qd * 4 + 3]);
            w1[qd * 2]     = pkbf(sB[qd * 4], sB[qd * 4 + 1]);
            w1[qd * 2 + 1] = pkbf(sB[qd * 4 + 2], sB[qd * 4 + 3]);
        }
        // PV: O^T += V^T x P^T, 4 k-steps of 16
#pragma unroll
        for (int ks = 0; ks < 4; ks++) {
            const int a4 = (ks & 1) * 4;
            unsigned int oo0, oo1, ss0, ss1;
            if ((ks >> 1) == 0) {
                oo0 = hi ? w0[a4 + 2] : w0[a4];
                oo1 = hi ? w0[a4 + 3] : w0[a4 + 1];
                ss0 = hi ? w0[a4] : w0[a4 + 2];
                ss1 = hi ? w0[a4 + 1] : w0[a4 + 3];
            } else {
                oo0 = hi ? w1[a4 + 2] : w1[a4];
                oo1 = hi ? w1[a4 + 3] : w1[a4 + 1];
                ss0 = hi ? w1[a4] : w1[a4 + 2];
                ss1 = hi ? w1[a4 + 1] : w1[a4 + 3];
            }
            unsigned int x0 = (unsigned int)__shfl_xor((int)ss0, 32);
            unsigned int x1 = (unsigned int)__shfl_xor((int)ss1, 32);
            union { unsigned int w[4]; bf16x8 v; } fr;
            fr.w[0] = hi ? x0 : oo0;
            fr.w[1] = hi ? x1 : oo1;
            fr.w[2] = hi ? oo0 : x0;
            fr.w[3] = hi ? oo1 : x1;
#pragma unroll
            for (int dt = 0; dt < 4; dt++) {
                int e = (dt * 32 + l31) * 64 + ((ks * 16 + hi * 8) ^ swr);
                bf16x8 vf = *(const bf16x8*)&Vl[e];
                o[dt] = MFMA32(vf, fr.v, o[dt]);
            }
        }
    }
    // permuted, per-lane-contiguous epilogue: lane owns 256B (4 full lines)
    size_t obase = ((size_t)(z * 16 + h) * 1024 + q) * 128 + hi * 64;
#pragma unroll
    for (int dt = 0; dt < 4; dt++) {
#pragma unroll
        for (int c = 0; c < 4; c++) {
            float4 f = make_float4(o[dt][4 * c], o[dt][4 * c + 1],
                                   o[dt][4 * c + 2], o[dt][4 * c + 3]);
            *(float4*)&Opart[obase + dt * 16 + c * 4] = f;
        }
    }
    if (hi == 0) MLpart[(size_t)(z * 16 + h) * 1024 + q] = make_float2(mm, ll);
}

// ---------------- combine 6 partials -> Ob bf16 [q][h*128+d] ----------------
// Opart p-index: p = hi*64 + dt*16 + c*4 + j  <->  d = dt*32 + 8c + 4hi + j.
// A float4 at aligned p is 4 consecutive d.
__global__ __launch_bounds__(256) void k_combine(
    const float* __restrict__ Opart, const float2* __restrict__ MLpart,
    bf16* __restrict__ Ob) {
    int q = blockIdx.x, t = threadIdx.x;
    int h = t >> 4, pb = (t & 15) * 8;
    int hi = pb >> 6, dt = (pb >> 4) & 3, c = (pb >> 2) & 3;
    int da = dt * 32 + 8 * c + 4 * hi;        // for float4 at pb
    int db = dt * 32 + 8 * (c + 1) + 4 * hi;  // for float4 at pb+4
    float m[6], l[6];
#pragma unroll
    for (int z = 0; z < 6; z++) {
        float2 v = MLpart[(size_t)(z * 16 + h) * 1024 + q];
        m[z] = v.x; l[z] = v.y;
    }
    float M = -1e30f;
#pragma unroll
    for (int z = 0; z < 6; z++) M = fmaxf(M, m[z]);
    float e[6], den = 0.f;
#pragma unroll
    for (int z = 0; z < 6; z++) { e[z] = exp2f(m[z] - M); den += e[z] * l[z]; }
    float inv = 1.0f / den;
    float acc[8] = {};
#pragma unroll
    for (int z = 0; z < 6; z++) {
        const float4* p = (const float4*)&Opart[((size_t)(z * 16 + h) * 1024 + q) * 128 + pb];
        float4 a = p[0], b2 = p[1];
        float s = e[z] * inv;
        acc[0] += a.x * s; acc[1] += a.y * s; acc[2] += a.z * s; acc[3] += a.w * s;
        acc[4] += b2.x * s; acc[5] += b2.y * s; acc[6] += b2.z * s; acc[7] += b2.w * s;
    }
    bf16x4 oa, ob;
#pragma unroll
    for (int j = 0; j < 4; j++) { oa[j] = (bf16)acc[j]; ob[j] = (bf16)acc[4 + j]; }
    *(bf16x4*)&Ob[(size_t)q * 2048 + h * 128 + da] = oa;
    *(bf16x4*)&Ob[(size_t)q * 2048 + h * 128 + db] = ob;
}

extern "C" void kernel_launch(void* const* d_in, const int* in_sizes, int n_in,
                              void* d_out, int out_size, void* d_ws, size_t ws_size,
                              hipStream_t stream) {
    const float* x       = (const float*)d_in[0];
    const float* cache_k = (const float*)d_in[1];
    const float* cache_v = (const float*)d_in[2];
    const float* theta   = (const float*)d_in[5];
    const float* Wq = (const float*)d_in[6];
    const float* bq = (const float*)d_in[7];
    const float* Wk = (const float*)d_in[8];
    const float* bk = (const float*)d_in[9];
    const float* Wv = (const float*)d_in[10];
    const float* bv = (const float*)d_in[11];
    const float* Wo = (const float*)d_in[12];
    const float* bo = (const float*)d_in[13];
    const float* gq = (const float*)d_in[14];
    const float* gk = (const float*)d_in[15];
    float* out = (float*)d_out;

    // ws layout (132 MB). WoT placed before WqT so WqT..vraw (48MB) is a
    // contiguous dead region at flash time -> Opart overlay.
    bf16* xbf = (bf16*)d_ws;                 // 4 MB; dead after QKV gemm -> MLpart
    bf16* WoT = xbf + 2097152;               // 8 MB (alive until final gemm)
    bf16* WqT = WoT + 4194304;               // 8 MB
    bf16* WkT = WqT + 4194304;
    bf16* WvT = WkT + 4194304;
    float* qraw = (float*)(WvT + 4194304);   // 8 MB each
    float* kraw = qraw + 2097152;
    float* vraw = kraw + 2097152;
    bf16* Qb = (bf16*)(vraw + 2097152);      // [16][1024][128]
    bf16* Kb = Qb + 2097152;                 // [16][8192][128]
    bf16* Vt = Kb + 16777216;                // [16][128][8192]
    bf16* Ob = Vt + 16777216;                // [1024][2048]

    float* Opart = (float*)WqT;              // [6][16][1024][128] fp32 = 48 MB
    float2* MLpart = (float2*)xbf;           // [6][16][1024] float2 = 768 KB

    k_cvt_x<<<1024, 256, 0, stream>>>(x, xbf);
    k_wt<<<dim3(32, 32), 256, 0, stream>>>(Wq, WqT);
    k_wt<<<dim3(32, 32), 256, 0, stream>>>(Wk, WkT);
    k_wt<<<dim3(32, 32), 256, 0, stream>>>(Wv, WvT);
    k_wt<<<dim3(32, 32), 256, 0, stream>>>(Wo, WoT);
    k_gemm<<<dim3(16, 8, 3), 256, 0, stream>>>(xbf, WqT, WkT, WvT, bq, bk, bv, qraw, kraw, vraw);
    k_normrope<<<1024, 256, 0, stream>>>(qraw, kraw, gq, gk, theta, Qb, Kb);
    k_vtrans<<<dim3(128, 16), 256, 0, stream>>>(vraw, cache_v, Vt);
    k_repack_k<<<7168, 256, 0, stream>>>(cache_k, Kb);
    k_flash<<<768, 256, 0, stream>>>(Qb, Kb, Vt, Opart, MLpart);
    k_combine<<<1024, 256, 0, stream>>>(Opart, MLpart, Ob);
    k_gemm<<<dim3(16, 8, 1), 256, 0, stream>>>(Ob, WoT, WoT, WoT, bo, bo, bo, out, out, out);
}

// Round 7
// 269.018 us; speedup vs baseline: 1.1784x; 1.1674x over previous
//
#include <hip/hip_runtime.h>

typedef __bf16 bf16;
typedef bf16 bf16x8 __attribute__((ext_vector_type(8)));
typedef bf16 bf16x4 __attribute__((ext_vector_type(4)));
typedef float f32x4 __attribute__((ext_vector_type(4)));
typedef float f32x16 __attribute__((ext_vector_type(16)));

#define MFMA16(a, b, c) __builtin_amdgcn_mfma_f32_16x16x32_bf16(a, b, c, 0, 0, 0)
#define MFMA32(a, b, c) __builtin_amdgcn_mfma_f32_32x32x16_bf16(a, b, c, 0, 0, 0)

__device__ __forceinline__ void async16(const bf16* g, bf16* l) {
    __builtin_amdgcn_global_load_lds(
        (const __attribute__((address_space(1))) unsigned int*)(g),
        (__attribute__((address_space(3))) unsigned int*)(l), 16, 0, 0);
}

__device__ __forceinline__ unsigned int pkbf(float a, float b) {
    union { bf16 h[2]; unsigned int u; } x;
    x.h[0] = (bf16)a; x.h[1] = (bf16)b;
    return x.u;
}

// ---------------- x -> bf16 ----------------
__global__ __launch_bounds__(256) void k_cvt_x(const float* __restrict__ x, bf16* __restrict__ o) {
    int i = (blockIdx.x * 256 + threadIdx.x) * 8;
    const float4* p = (const float4*)(x + i);
    float4 a = p[0], b = p[1];
    bf16x8 v;
    v[0] = (bf16)a.x; v[1] = (bf16)a.y; v[2] = (bf16)a.z; v[3] = (bf16)a.w;
    v[4] = (bf16)b.x; v[5] = (bf16)b.y; v[6] = (bf16)b.z; v[7] = (bf16)b.w;
    *(bf16x8*)(o + i) = v;
}

// ---------------- W [K][N] fp32 -> WT [N][K] bf16 ----------------
__global__ __launch_bounds__(256) void k_wt(const float* __restrict__ W, bf16* __restrict__ WT) {
    __shared__ bf16 lt[64][72];
    int t = threadIdx.x;
    int n0 = blockIdx.x * 64, k0 = blockIdx.y * 64;
#pragma unroll
    for (int j = 0; j < 4; j++) {
        int idx = t + 256 * j;
        int r = idx >> 4;
        int c4 = (idx & 15) << 2;
        float4 v = *(const float4*)&W[(size_t)(k0 + r) * 2048 + n0 + c4];
        lt[r][c4] = (bf16)v.x; lt[r][c4 + 1] = (bf16)v.y;
        lt[r][c4 + 2] = (bf16)v.z; lt[r][c4 + 3] = (bf16)v.w;
    }
    __syncthreads();
#pragma unroll
    for (int j = 0; j < 4; j++) {
        int idx = t + 256 * j;
        int n = idx >> 4;
        int k4 = (idx & 15) << 2;
        bf16x4 o;
        o[0] = lt[k4][n]; o[1] = lt[k4 + 1][n]; o[2] = lt[k4 + 2][n]; o[3] = lt[k4 + 3][n];
        *(bf16x4*)&WT[(size_t)(n0 + n) * 2048 + k0 + k4] = o;
    }
}

// ---------------- GEMM (m97 template): C[1024][2048] = A * Bt^T + bias, fp32 out ----
__global__ __launch_bounds__(256) void k_gemm(
    const bf16* __restrict__ A,
    const bf16* __restrict__ B0, const bf16* __restrict__ B1, const bf16* __restrict__ B2,
    const float* __restrict__ c0, const float* __restrict__ c1, const float* __restrict__ c2,
    float* __restrict__ D0, float* __restrict__ D1, float* __restrict__ D2) {
    const int N = 2048, K = 2048;
    const bf16* Bt = blockIdx.z == 0 ? B0 : (blockIdx.z == 1 ? B1 : B2);
    const float* bias = blockIdx.z == 0 ? c0 : (blockIdx.z == 1 ? c1 : c2);
    float* D = blockIdx.z == 0 ? D0 : (blockIdx.z == 1 ? D1 : D2);
    __shared__ bf16 Al[128 * 32];
    __shared__ bf16 Bl[128 * 32];
    int t = threadIdx.x;
    int lane = t & 63, w = t >> 6;
    int l15 = lane & 15, g = lane >> 4;
    int wr = w >> 1, wc = w & 1;
    int m0 = blockIdx.y * 128, n0 = blockIdx.x * 128;
    f32x4 acc[4][4] = {};
    int arow = t >> 2, acol = (t & 3) * 8;
    for (int k0 = 0; k0 < K; k0 += 32) {
        async16(&A[(size_t)(m0 + arow) * K + k0 + acol], Al + t * 8);
        async16(&A[(size_t)(m0 + 64 + arow) * K + k0 + acol], Al + 2048 + t * 8);
        async16(&Bt[(size_t)(n0 + arow) * K + k0 + acol], Bl + t * 8);
        async16(&Bt[(size_t)(n0 + 64 + arow) * K + k0 + acol], Bl + 2048 + t * 8);
        __syncthreads();
        bf16x8 af[4], bfr[4];
#pragma unroll
        for (int i = 0; i < 4; i++) af[i] = *(const bf16x8*)&Al[(wr * 64 + i * 16 + l15) * 32 + g * 8];
#pragma unroll
        for (int i = 0; i < 4; i++) bfr[i] = *(const bf16x8*)&Bl[(wc * 64 + i * 16 + l15) * 32 + g * 8];
#pragma unroll
        for (int mi = 0; mi < 4; mi++)
#pragma unroll
            for (int ni = 0; ni < 4; ni++)
                acc[mi][ni] = MFMA16(af[mi], bfr[ni], acc[mi][ni]);
        __syncthreads();
    }
#pragma unroll
    for (int mi = 0; mi < 4; mi++) {
#pragma unroll
        for (int ni = 0; ni < 4; ni++) {
            int n = n0 + wc * 64 + ni * 16 + l15;
            float bv = bias[n];
#pragma unroll
            for (int r = 0; r < 4; r++) {
                int m = m0 + wr * 64 + mi * 16 + g * 4 + r;
                D[(size_t)m * N + n] = acc[mi][ni][r] + bv;
            }
        }
    }
}

// ---------------- rmsnorm + rope (Q scale folded with log2e) ----------------
__global__ __launch_bounds__(256) void k_normrope(
    const float* __restrict__ qraw, const float* __restrict__ kraw,
    const float* __restrict__ gq, const float* __restrict__ gk,
    const float* __restrict__ theta,
    bf16* __restrict__ Qb, bf16* __restrict__ Kb) {
    int l = blockIdx.x, t = threadIdx.x;
    int lane = t & 63, w = t >> 6;
    int c = t * 8;
    float qv[8], kv[8];
    const float4* qp = (const float4*)(qraw + (size_t)l * 2048 + c);
    const float4* kp = (const float4*)(kraw + (size_t)l * 2048 + c);
    float4 a;
    a = qp[0]; qv[0] = a.x; qv[1] = a.y; qv[2] = a.z; qv[3] = a.w;
    a = qp[1]; qv[4] = a.x; qv[5] = a.y; qv[6] = a.z; qv[7] = a.w;
    a = kp[0]; kv[0] = a.x; kv[1] = a.y; kv[2] = a.z; kv[3] = a.w;
    a = kp[1]; kv[4] = a.x; kv[5] = a.y; kv[6] = a.z; kv[7] = a.w;
    float ssq = 0.f, ssk = 0.f;
#pragma unroll
    for (int j = 0; j < 8; j++) { ssq += qv[j] * qv[j]; ssk += kv[j] * kv[j]; }
#pragma unroll
    for (int m = 1; m < 64; m <<= 1) { ssq += __shfl_xor(ssq, m); ssk += __shfl_xor(ssk, m); }
    __shared__ float rq[4], rk[4];
    if (lane == 0) { rq[w] = ssq; rk[w] = ssk; }
    __syncthreads();
    ssq = rq[0] + rq[1] + rq[2] + rq[3];
    ssk = rk[0] + rk[1] + rk[2] + rk[3];
    float iq = rsqrtf(ssq * (1.0f / 2048.0f) + 1e-6f);
    float ik = rsqrtf(ssk * (1.0f / 2048.0f) + 1e-6f);
#pragma unroll
    for (int j = 0; j < 8; j++) { qv[j] *= iq * gq[c + j]; kv[j] *= ik * gk[c + j]; }
    int h = c >> 7, dd = c & 127;
    bf16x8 qo, ko;
    // log2(e) / sqrt(128): softmax runs in base-2
    const float SC = 1.4426950408889634f / 11.313708498984761f;
#pragma unroll
    for (int p = 0; p < 4; p++) {
        float th = theta[l * 64 + (dd >> 1) + p];
        float sn, cs;
        __sincosf(th, &sn, &cs);
        float qr = qv[2 * p] * cs - qv[2 * p + 1] * sn;
        float qi = qv[2 * p] * sn + qv[2 * p + 1] * cs;
        float kr = kv[2 * p] * cs - kv[2 * p + 1] * sn;
        float ki = kv[2 * p] * sn + kv[2 * p + 1] * cs;
        qo[2 * p] = (bf16)(qr * SC); qo[2 * p + 1] = (bf16)(qi * SC);
        ko[2 * p] = (bf16)kr;        ko[2 * p + 1] = (bf16)ki;
    }
    *(bf16x8*)&Qb[(size_t)h * 131072 + (size_t)l * 128 + dd] = qo;
    *(bf16x8*)&Kb[(size_t)h * 1048576 + (size_t)l * 128 + dd] = ko;
}

// ---------------- V transpose: [s][n*128+d] fp32 -> Vt[n][d][s] bf16 ----------------
__global__ __launch_bounds__(256) void k_vtrans(
    const float* __restrict__ vraw, const float* __restrict__ cache_v, bf16* __restrict__ Vt) {
    int st = blockIdx.x;
    int n = blockIdx.y;
    int s0 = st * 64;
    const float* src = (s0 < 1024) ? (vraw + (size_t)s0 * 2048) : (cache_v + (size_t)s0 * 2048);
    __shared__ bf16 lt[64][132];
    int t = threadIdx.x;
#pragma unroll
    for (int j = 0; j < 8; j++) {
        int idx = t + 256 * j;
        int i = idx >> 5;
        int d4 = (idx & 31) << 2;
        float4 v = *(const float4*)&src[(size_t)i * 2048 + n * 128 + d4];
        lt[i][d4] = (bf16)v.x; lt[i][d4 + 1] = (bf16)v.y;
        lt[i][d4 + 2] = (bf16)v.z; lt[i][d4 + 3] = (bf16)v.w;
    }
    __syncthreads();
    int d = t >> 1, sh = (t & 1) << 5;
    bf16* dst = Vt + (size_t)n * 1048576 + (size_t)d * 8192 + s0 + sh;
#pragma unroll
    for (int q = 0; q < 4; q++) {
        bf16x8 o;
#pragma unroll
        for (int e = 0; e < 8; e++) o[e] = lt[sh + q * 8 + e][d];
        *(bf16x8*)&dst[q * 8] = o;
    }
}

// ---------------- cache_k repack: [s][n][d] fp32 -> Kb[n][s][d] bf16 (s >= 1024) ----------------
__global__ __launch_bounds__(256) void k_repack_k(const float* __restrict__ cache_k, bf16* __restrict__ Kb) {
    int s = 1024 + blockIdx.x;
    int t = threadIdx.x;
    int e = t * 8;
    int n = e >> 7, d = e & 127;
    const float4* p = (const float4*)&cache_k[(size_t)s * 2048 + e];
    float4 a = p[0], b = p[1];
    bf16x8 v;
    v[0] = (bf16)a.x; v[1] = (bf16)a.y; v[2] = (bf16)a.z; v[3] = (bf16)a.w;
    v[4] = (bf16)b.x; v[5] = (bf16)b.y; v[6] = (bf16)b.z; v[7] = (bf16)b.w;
    *(bf16x8*)&Kb[(size_t)n * 1048576 + (size_t)s * 128 + d] = v;
}

// ---------------- flash attention: swapped 32x32 MFMA, in-register softmax ----------------
// flat grid 512 = 256 CU x 2 blocks (launch_bounds(256,2): no spill squeeze —
// R5/R6 lesson: (256,3) cut VGPR 104->84 and spilled the acc in the K-loop,
// +240MB HBM writes and -30% MfmaUtil).
// XCD-aware remap (b&7 = XCD): 8 qblks sharing an (h,z) K/V slice co-locate.
// z=4 splits of 32 KV-tiles each. Reg-staged T14 split.
__global__ __launch_bounds__(256, 2) void k_flash(
    const bf16* __restrict__ Qb, const bf16* __restrict__ Kb, const bf16* __restrict__ Vt,
    float* __restrict__ Opart, float2* __restrict__ MLpart) {
    int b = blockIdx.x;
    int cx = b & 7, jj = b >> 3;           // cx = XCD (heuristic), jj = 0..63
    int p = cx + 8 * (jj >> 3);            // (h,z) pair 0..63
    int qb = jj & 7;
    int h = p & 15, z = p >> 4;            // z = 0..3
    int q0 = qb * 128;
    int t = threadIdx.x;
    int lane = t & 63, wq = t >> 6;
    int l31 = lane & 31, hi = lane >> 5;
    __shared__ bf16 Kl[64 * 128];   // [k][d], 16B slots XOR-swizzled by row&7
    __shared__ bf16 Vl[128 * 64];   // [d][s], 16B slots XOR-swizzled by d&7
    const bf16* Kh = Kb + (size_t)h * 1048576;
    const bf16* Vh = Vt + (size_t)h * 1048576;
    int q = q0 + wq * 32 + l31;
    bf16x8 qf[8];
#pragma unroll
    for (int db = 0; db < 8; db++)
        qf[db] = *(const bf16x8*)&Qb[(size_t)h * 131072 + (size_t)q * 128 + db * 16 + hi * 8];
    f32x16 o[4] = {};
    float mm = -1e30f, ll = 0.f;
    int krow = t >> 4;
    int kcol = (t & 15) * 8;
    int kdst = krow * 128 + (((t & 15) ^ (krow & 7)) * 8);
    int vrow = t >> 3;
    int vcol = (t & 7) * 8;
    int vdst = vrow * 64 + (((t & 7) ^ (vrow & 7)) * 8);
    int swr = (l31 & 7) << 3;
    int it0 = z * 32, it1 = it0 + 32;
    bf16x8 kst[4], vst[4];
    {
        int s0 = it0 * 64;
#pragma unroll
        for (int j = 0; j < 4; j++)
            kst[j] = *(const bf16x8*)&Kh[(size_t)(s0 + krow + 16 * j) * 128 + kcol];
#pragma unroll
        for (int j = 0; j < 4; j++)
            vst[j] = *(const bf16x8*)&Vh[(size_t)(vrow + 32 * j) * 8192 + s0 + vcol];
    }
    for (int it = it0; it < it1; ++it) {
        __syncthreads();   // previous iteration's LDS reads complete
#pragma unroll
        for (int j = 0; j < 4; j++) *(bf16x8*)&Kl[kdst + j * 2048] = kst[j];
#pragma unroll
        for (int j = 0; j < 4; j++) *(bf16x8*)&Vl[vdst + j * 2048] = vst[j];
        __syncthreads();   // LDS tile ready
        if (it + 1 < it1) {
            int s1 = (it + 1) * 64;
#pragma unroll
            for (int j = 0; j < 4; j++)
                kst[j] = *(const bf16x8*)&Kh[(size_t)(s1 + krow + 16 * j) * 128 + kcol];
#pragma unroll
            for (int j = 0; j < 4; j++)
                vst[j] = *(const bf16x8*)&Vh[(size_t)(vrow + 32 * j) * 8192 + s1 + vcol];
        }
        // QK^T swapped: sA = K[0:32] x Q^T, sB = K[32:64] x Q^T
        f32x16 sA = {}, sB = {};
#pragma unroll
        for (int db = 0; db < 8; db++) {
            int doff = (db * 16 + hi * 8) ^ swr;
            bf16x8 ka = *(const bf16x8*)&Kl[l31 * 128 + doff];
            bf16x8 kb = *(const bf16x8*)&Kl[(32 + l31) * 128 + doff];
            sA = MFMA32(ka, qf[db], sA);
            sB = MFMA32(kb, qf[db], sB);
        }
        // in-register softmax (base-2), defer-max
        float tm = -1e30f;
#pragma unroll
        for (int r = 0; r < 16; r++) { tm = fmaxf(tm, sA[r]); tm = fmaxf(tm, sB[r]); }
        tm = fmaxf(tm, __shfl_xor(tm, 32));
        if (__any(tm > mm + 11.5416f)) {
            float mn = fmaxf(mm, tm);
            float al = exp2f(mm - mn);
#pragma unroll
            for (int dt = 0; dt < 4; dt++)
#pragma unroll
                for (int r = 0; r < 16; r++) o[dt][r] *= al;
            ll *= al; mm = mn;
        }
        float ps = 0.f;
#pragma unroll
        for (int r = 0; r < 16; r++) { sA[r] = exp2f(sA[r] - mm); ps += sA[r]; }
#pragma unroll
        for (int r = 0; r < 16; r++) { sB[r] = exp2f(sB[r] - mm); ps += sB[r]; }
        ll += ps + __shfl_xor(ps, 32);
        // pack P to bf16 words: w[2*qd+j] = regs 4qd+2j, 4qd+2j+1
        unsigned int w0[8], w1[8];
#pragma unroll
        for (int qd = 0; qd < 4; qd++) {
            w0[qd * 2]     = pkbf(sA[qd * 4], sA[qd * 4 + 1]);
            w0[qd * 2 + 1] = pkbf(sA[qd * 4 + 2], sA[qd * 4 + 3]);
            w1[qd * 2]     = pkbf(sB[qd * 4], sB[qd * 4 + 1]);
            w1[qd * 2 + 1] = pkbf(sB[qd * 4 + 2], sB[qd * 4 + 3]);
        }
        // PV: O^T += V^T x P^T, 4 k-steps of 16
#pragma unroll
        for (int ks = 0; ks < 4; ks++) {
            const int a4 = (ks & 1) * 4;
            unsigned int oo0, oo1, ss0, ss1;
            if ((ks >> 1) == 0) {
                oo0 = hi ? w0[a4 + 2] : w0[a4];
                oo1 = hi ? w0[a4 + 3] : w0[a4 + 1];
                ss0 = hi ? w0[a4] : w0[a4 + 2];
                ss1 = hi ? w0[a4 + 1] : w0[a4 + 3];
            } else {
                oo0 = hi ? w1[a4 + 2] : w1[a4];
                oo1 = hi ? w1[a4 + 3] : w1[a4 + 1];
                ss0 = hi ? w1[a4] : w1[a4 + 2];
                ss1 = hi ? w1[a4 + 1] : w1[a4 + 3];
            }
            unsigned int x0 = (unsigned int)__shfl_xor((int)ss0, 32);
            unsigned int x1 = (unsigned int)__shfl_xor((int)ss1, 32);
            union { unsigned int w[4]; bf16x8 v; } fr;
            fr.w[0] = hi ? x0 : oo0;
            fr.w[1] = hi ? x1 : oo1;
            fr.w[2] = hi ? oo0 : x0;
            fr.w[3] = hi ? oo1 : x1;
#pragma unroll
            for (int dt = 0; dt < 4; dt++) {
                int e = (dt * 32 + l31) * 64 + ((ks * 16 + hi * 8) ^ swr);
                bf16x8 vf = *(const bf16x8*)&Vl[e];
                o[dt] = MFMA32(vf, fr.v, o[dt]);
            }
        }
    }
    // permuted, per-lane-contiguous epilogue: lane owns 256B (4 full lines)
    size_t obase = ((size_t)(z * 16 + h) * 1024 + q) * 128 + hi * 64;
#pragma unroll
    for (int dt = 0; dt < 4; dt++) {
#pragma unroll
        for (int c = 0; c < 4; c++) {
            float4 f = make_float4(o[dt][4 * c], o[dt][4 * c + 1],
                                   o[dt][4 * c + 2], o[dt][4 * c + 3]);
            *(float4*)&Opart[obase + dt * 16 + c * 4] = f;
        }
    }
    if (hi == 0) MLpart[(size_t)(z * 16 + h) * 1024 + q] = make_float2(mm, ll);
}

// ---------------- combine 4 partials -> Ob bf16 [q][h*128+d] ----------------
// Opart p-index: p = hi*64 + dt*16 + c*4 + j  <->  d = dt*32 + 8c + 4hi + j.
__global__ __launch_bounds__(256) void k_combine(
    const float* __restrict__ Opart, const float2* __restrict__ MLpart,
    bf16* __restrict__ Ob) {
    int q = blockIdx.x, t = threadIdx.x;
    int h = t >> 4, pb = (t & 15) * 8;
    int hi = pb >> 6, dt = (pb >> 4) & 3, c = (pb >> 2) & 3;
    int da = dt * 32 + 8 * c + 4 * hi;        // for float4 at pb
    int db = dt * 32 + 8 * (c + 1) + 4 * hi;  // for float4 at pb+4
    float m[4], l[4];
#pragma unroll
    for (int z = 0; z < 4; z++) {
        float2 v = MLpart[(size_t)(z * 16 + h) * 1024 + q];
        m[z] = v.x; l[z] = v.y;
    }
    float M = -1e30f;
#pragma unroll
    for (int z = 0; z < 4; z++) M = fmaxf(M, m[z]);
    float e[4], den = 0.f;
#pragma unroll
    for (int z = 0; z < 4; z++) { e[z] = exp2f(m[z] - M); den += e[z] * l[z]; }
    float inv = 1.0f / den;
    float acc[8] = {};
#pragma unroll
    for (int z = 0; z < 4; z++) {
        const float4* p = (const float4*)&Opart[((size_t)(z * 16 + h) * 1024 + q) * 128 + pb];
        float4 a = p[0], b2 = p[1];
        float s = e[z] * inv;
        acc[0] += a.x * s; acc[1] += a.y * s; acc[2] += a.z * s; acc[3] += a.w * s;
        acc[4] += b2.x * s; acc[5] += b2.y * s; acc[6] += b2.z * s; acc[7] += b2.w * s;
    }
    bf16x4 oa, ob;
#pragma unroll
    for (int j = 0; j < 4; j++) { oa[j] = (bf16)acc[j]; ob[j] = (bf16)acc[4 + j]; }
    *(bf16x4*)&Ob[(size_t)q * 2048 + h * 128 + da] = oa;
    *(bf16x4*)&Ob[(size_t)q * 2048 + h * 128 + db] = ob;
}

extern "C" void kernel_launch(void* const* d_in, const int* in_sizes, int n_in,
                              void* d_out, int out_size, void* d_ws, size_t ws_size,
                              hipStream_t stream) {
    const float* x       = (const float*)d_in[0];
    const float* cache_k = (const float*)d_in[1];
    const float* cache_v = (const float*)d_in[2];
    const float* theta   = (const float*)d_in[5];
    const float* Wq = (const float*)d_in[6];
    const float* bq = (const float*)d_in[7];
    const float* Wk = (const float*)d_in[8];
    const float* bk = (const float*)d_in[9];
    const float* Wv = (const float*)d_in[10];
    const float* bv = (const float*)d_in[11];
    const float* Wo = (const float*)d_in[12];
    const float* bo = (const float*)d_in[13];
    const float* gq = (const float*)d_in[14];
    const float* gk = (const float*)d_in[15];
    float* out = (float*)d_out;

    // ws layout (132 MB). WoT placed before WqT so WqT..vraw (48MB) is a
    // contiguous dead region at flash time -> Opart overlay.
    bf16* xbf = (bf16*)d_ws;                 // 4 MB; dead after QKV gemm -> MLpart
    bf16* WoT = xbf + 2097152;               // 8 MB (alive until final gemm)
    bf16* WqT = WoT + 4194304;               // 8 MB
    bf16* WkT = WqT + 4194304;
    bf16* WvT = WkT + 4194304;
    float* qraw = (float*)(WvT + 4194304);   // 8 MB each
    float* kraw = qraw + 2097152;
    float* vraw = kraw + 2097152;
    bf16* Qb = (bf16*)(vraw + 2097152);      // [16][1024][128]
    bf16* Kb = Qb + 2097152;                 // [16][8192][128]
    bf16* Vt = Kb + 16777216;                // [16][128][8192]
    bf16* Ob = Vt + 16777216;                // [1024][2048]

    float* Opart = (float*)WqT;              // [4][16][1024][128] fp32 = 32 MB
    float2* MLpart = (float2*)xbf;           // [4][16][1024] float2 = 512 KB

    k_cvt_x<<<1024, 256, 0, stream>>>(x, xbf);
    k_wt<<<dim3(32, 32), 256, 0, stream>>>(Wq, WqT);
    k_wt<<<dim3(32, 32), 256, 0, stream>>>(Wk, WkT);
    k_wt<<<dim3(32, 32), 256, 0, stream>>>(Wv, WvT);
    k_wt<<<dim3(32, 32), 256, 0, stream>>>(Wo, WoT);
    k_gemm<<<dim3(16, 8, 3), 256, 0, stream>>>(xbf, WqT, WkT, WvT, bq, bk, bv, qraw, kraw, vraw);
    k_normrope<<<1024, 256, 0, stream>>>(qraw, kraw, gq, gk, theta, Qb, Kb);
    k_vtrans<<<dim3(128, 16), 256, 0, stream>>>(vraw, cache_v, Vt);
    k_repack_k<<<7168, 256, 0, stream>>>(cache_k, Kb);
    k_flash<<<512, 256, 0, stream>>>(Qb, Kb, Vt, Opart, MLpart);
    k_combine<<<1024, 256, 0, stream>>>(Opart, MLpart, Ob);
    k_gemm<<<dim3(16, 8, 1), 256, 0, stream>>>(Ob, WoT, WoT, WoT, bo, bo, bo, out, out, out);
}

// Round 8
// 242.020 us; speedup vs baseline: 1.3098x; 1.1116x over previous
//
#include <hip/hip_runtime.h>

typedef __bf16 bf16;
typedef bf16 bf16x8 __attribute__((ext_vector_type(8)));
typedef bf16 bf16x4 __attribute__((ext_vector_type(4)));
typedef float f32x4 __attribute__((ext_vector_type(4)));
typedef float f32x16 __attribute__((ext_vector_type(16)));

#define MFMA16(a, b, c) __builtin_amdgcn_mfma_f32_16x16x32_bf16(a, b, c, 0, 0, 0)
#define MFMA32(a, b, c) __builtin_amdgcn_mfma_f32_32x32x16_bf16(a, b, c, 0, 0, 0)

__device__ __forceinline__ void async16(const bf16* g, bf16* l) {
    __builtin_amdgcn_global_load_lds(
        (const __attribute__((address_space(1))) unsigned int*)(g),
        (__attribute__((address_space(3))) unsigned int*)(l), 16, 0, 0);
}

__device__ __forceinline__ unsigned int pkbf(float a, float b) {
    union { bf16 h[2]; unsigned int u; } x;
    x.h[0] = (bf16)a; x.h[1] = (bf16)b;
    return x.u;
}

// ---------------- fused prep: x->bf16 (blocks 0..1023) + 4x W^T (blocks 1024..5119) ----
__global__ __launch_bounds__(256) void k_prep(
    const float* __restrict__ x, bf16* __restrict__ xbf,
    const float* __restrict__ Wq, const float* __restrict__ Wk,
    const float* __restrict__ Wv, const float* __restrict__ Wo,
    bf16* __restrict__ WqT, bf16* __restrict__ WkT,
    bf16* __restrict__ WvT, bf16* __restrict__ WoT) {
    __shared__ bf16 lt[64][72];
    int b = blockIdx.x, t = threadIdx.x;
    if (b < 1024) {
        int i = (b * 256 + t) * 8;
        const float4* p = (const float4*)(x + i);
        float4 a = p[0], c = p[1];
        bf16x8 v;
        v[0] = (bf16)a.x; v[1] = (bf16)a.y; v[2] = (bf16)a.z; v[3] = (bf16)a.w;
        v[4] = (bf16)c.x; v[5] = (bf16)c.y; v[6] = (bf16)c.z; v[7] = (bf16)c.w;
        *(bf16x8*)(xbf + i) = v;
        return;
    }
    int wb = b - 1024;
    int wid = wb >> 10, rem = wb & 1023;
    const float* W = wid == 0 ? Wq : (wid == 1 ? Wk : (wid == 2 ? Wv : Wo));
    bf16* WT = wid == 0 ? WqT : (wid == 1 ? WkT : (wid == 2 ? WvT : WoT));
    int n0 = (rem & 31) * 64, k0 = (rem >> 5) * 64;
#pragma unroll
    for (int j = 0; j < 4; j++) {
        int idx = t + 256 * j;
        int r = idx >> 4;
        int c4 = (idx & 15) << 2;
        float4 v = *(const float4*)&W[(size_t)(k0 + r) * 2048 + n0 + c4];
        lt[r][c4] = (bf16)v.x; lt[r][c4 + 1] = (bf16)v.y;
        lt[r][c4 + 2] = (bf16)v.z; lt[r][c4 + 3] = (bf16)v.w;
    }
    __syncthreads();
#pragma unroll
    for (int j = 0; j < 4; j++) {
        int idx = t + 256 * j;
        int n = idx >> 4;
        int k4 = (idx & 15) << 2;
        bf16x4 o;
        o[0] = lt[k4][n]; o[1] = lt[k4 + 1][n]; o[2] = lt[k4 + 2][n]; o[3] = lt[k4 + 3][n];
        *(bf16x4*)&WT[(size_t)(n0 + n) * 2048 + k0 + k4] = o;
    }
}

// ---------------- GEMM (m97 staging, 64x128 tile): C = A * Bt^T + bias, fp32 out ----
// grid (N/128, M/64, nz). QKV: nz=3 -> 768 blocks (3/CU). Out-proj: nz=1 -> 256 (1/CU).
__global__ __launch_bounds__(256) void k_gemm(
    const bf16* __restrict__ A,
    const bf16* __restrict__ B0, const bf16* __restrict__ B1, const bf16* __restrict__ B2,
    const float* __restrict__ c0, const float* __restrict__ c1, const float* __restrict__ c2,
    float* __restrict__ D0, float* __restrict__ D1, float* __restrict__ D2) {
    const int N = 2048, K = 2048;
    const bf16* Bt = blockIdx.z == 0 ? B0 : (blockIdx.z == 1 ? B1 : B2);
    const float* bias = blockIdx.z == 0 ? c0 : (blockIdx.z == 1 ? c1 : c2);
    float* D = blockIdx.z == 0 ? D0 : (blockIdx.z == 1 ? D1 : D2);
    __shared__ bf16 Al[64 * 32];    // 4 KB
    __shared__ bf16 Bl[128 * 32];   // 8 KB
    int t = threadIdx.x;
    int lane = t & 63, w = t >> 6;
    int l15 = lane & 15, g = lane >> 4;
    int wr = w >> 1, wc = w & 1;            // wave tile: 32 rows x 64 cols
    int m0 = blockIdx.y * 64, n0 = blockIdx.x * 128;
    f32x4 acc[2][4] = {};
    int arow = t >> 2, acol = (t & 3) * 8;
    for (int k0 = 0; k0 < K; k0 += 32) {
        async16(&A[(size_t)(m0 + arow) * K + k0 + acol], Al + t * 8);
        async16(&Bt[(size_t)(n0 + arow) * K + k0 + acol], Bl + t * 8);
        async16(&Bt[(size_t)(n0 + 64 + arow) * K + k0 + acol], Bl + 2048 + t * 8);
        __syncthreads();
        bf16x8 af[2], bfr[4];
#pragma unroll
        for (int i = 0; i < 2; i++) af[i] = *(const bf16x8*)&Al[(wr * 32 + i * 16 + l15) * 32 + g * 8];
#pragma unroll
        for (int i = 0; i < 4; i++) bfr[i] = *(const bf16x8*)&Bl[(wc * 64 + i * 16 + l15) * 32 + g * 8];
#pragma unroll
        for (int mi = 0; mi < 2; mi++)
#pragma unroll
            for (int ni = 0; ni < 4; ni++)
                acc[mi][ni] = MFMA16(af[mi], bfr[ni], acc[mi][ni]);
        __syncthreads();
    }
#pragma unroll
    for (int mi = 0; mi < 2; mi++) {
#pragma unroll
        for (int ni = 0; ni < 4; ni++) {
            int n = n0 + wc * 64 + ni * 16 + l15;
            float bv = bias[n];
#pragma unroll
            for (int r = 0; r < 4; r++) {
                int m = m0 + wr * 32 + mi * 16 + g * 4 + r;
                D[(size_t)m * N + n] = acc[mi][ni][r] + bv;
            }
        }
    }
}

// ---------------- fused post: normrope (0..1023) + vtrans (1024..3071) + repack_k (3072..10239) ----
__global__ __launch_bounds__(256) void k_post(
    const float* __restrict__ qraw, const float* __restrict__ kraw, const float* __restrict__ vraw,
    const float* __restrict__ cache_k, const float* __restrict__ cache_v,
    const float* __restrict__ gq, const float* __restrict__ gk,
    const float* __restrict__ theta,
    bf16* __restrict__ Qb, bf16* __restrict__ Kb, bf16* __restrict__ Vt) {
    __shared__ bf16 lt[64][132];
    __shared__ float rq[4], rk[4];
    int b = blockIdx.x, t = threadIdx.x;
    if (b < 1024) {
        // ---- rmsnorm + rope ----
        int l = b;
        int lane = t & 63, w = t >> 6;
        int c = t * 8;
        float qv[8], kv[8];
        const float4* qp = (const float4*)(qraw + (size_t)l * 2048 + c);
        const float4* kp = (const float4*)(kraw + (size_t)l * 2048 + c);
        float4 a;
        a = qp[0]; qv[0] = a.x; qv[1] = a.y; qv[2] = a.z; qv[3] = a.w;
        a = qp[1]; qv[4] = a.x; qv[5] = a.y; qv[6] = a.z; qv[7] = a.w;
        a = kp[0]; kv[0] = a.x; kv[1] = a.y; kv[2] = a.z; kv[3] = a.w;
        a = kp[1]; kv[4] = a.x; kv[5] = a.y; kv[6] = a.z; kv[7] = a.w;
        float ssq = 0.f, ssk = 0.f;
#pragma unroll
        for (int j = 0; j < 8; j++) { ssq += qv[j] * qv[j]; ssk += kv[j] * kv[j]; }
#pragma unroll
        for (int m = 1; m < 64; m <<= 1) { ssq += __shfl_xor(ssq, m); ssk += __shfl_xor(ssk, m); }
        if (lane == 0) { rq[w] = ssq; rk[w] = ssk; }
        __syncthreads();
        ssq = rq[0] + rq[1] + rq[2] + rq[3];
        ssk = rk[0] + rk[1] + rk[2] + rk[3];
        float iq = rsqrtf(ssq * (1.0f / 2048.0f) + 1e-6f);
        float ik = rsqrtf(ssk * (1.0f / 2048.0f) + 1e-6f);
#pragma unroll
        for (int j = 0; j < 8; j++) { qv[j] *= iq * gq[c + j]; kv[j] *= ik * gk[c + j]; }
        int h = c >> 7, dd = c & 127;
        bf16x8 qo, ko;
        const float SC = 1.4426950408889634f / 11.313708498984761f;  // log2e/sqrt(128)
#pragma unroll
        for (int p = 0; p < 4; p++) {
            float th = theta[l * 64 + (dd >> 1) + p];
            float sn, cs;
            __sincosf(th, &sn, &cs);
            float qr = qv[2 * p] * cs - qv[2 * p + 1] * sn;
            float qi = qv[2 * p] * sn + qv[2 * p + 1] * cs;
            float kr = kv[2 * p] * cs - kv[2 * p + 1] * sn;
            float ki = kv[2 * p] * sn + kv[2 * p + 1] * cs;
            qo[2 * p] = (bf16)(qr * SC); qo[2 * p + 1] = (bf16)(qi * SC);
            ko[2 * p] = (bf16)kr;        ko[2 * p + 1] = (bf16)ki;
        }
        *(bf16x8*)&Qb[(size_t)h * 131072 + (size_t)l * 128 + dd] = qo;
        *(bf16x8*)&Kb[(size_t)h * 1048576 + (size_t)l * 128 + dd] = ko;
        return;
    }
    if (b < 3072) {
        // ---- V transpose ----
        int vb = b - 1024;
        int st = vb & 127, n = vb >> 7;
        int s0 = st * 64;
        const float* src = (s0 < 1024) ? (vraw + (size_t)s0 * 2048) : (cache_v + (size_t)s0 * 2048);
#pragma unroll
        for (int j = 0; j < 8; j++) {
            int idx = t + 256 * j;
            int i = idx >> 5;
            int d4 = (idx & 31) << 2;
            float4 v = *(const float4*)&src[(size_t)i * 2048 + n * 128 + d4];
            lt[i][d4] = (bf16)v.x; lt[i][d4 + 1] = (bf16)v.y;
            lt[i][d4 + 2] = (bf16)v.z; lt[i][d4 + 3] = (bf16)v.w;
        }
        __syncthreads();
        int d = t >> 1, sh = (t & 1) << 5;
        bf16* dst = Vt + (size_t)n * 1048576 + (size_t)d * 8192 + s0 + sh;
#pragma unroll
        for (int q = 0; q < 4; q++) {
            bf16x8 o;
#pragma unroll
            for (int e = 0; e < 8; e++) o[e] = lt[sh + q * 8 + e][d];
            *(bf16x8*)&dst[q * 8] = o;
        }
        return;
    }
    // ---- cache_k repack (s >= 1024) ----
    int s = 1024 + (b - 3072);
    int e = t * 8;
    int n = e >> 7, d = e & 127;
    const float4* p = (const float4*)&cache_k[(size_t)s * 2048 + e];
    float4 a = p[0], c2 = p[1];
    bf16x8 v;
    v[0] = (bf16)a.x; v[1] = (bf16)a.y; v[2] = (bf16)a.z; v[3] = (bf16)a.w;
    v[4] = (bf16)c2.x; v[5] = (bf16)c2.y; v[6] = (bf16)c2.z; v[7] = (bf16)c2.w;
    *(bf16x8*)&Kb[(size_t)n * 1048576 + (size_t)s * 128 + d] = v;
}

// ---------------- flash attention: swapped 32x32 MFMA, in-register softmax ----------------
// flat grid 512 = 2 blocks/CU; launch_bounds(256,2) — NOT 3: the ~164-reg live
// set (incl 64-reg acc) spills under a 3-wave/EU cap (R5/R6: +240MB scratch).
// XCD-aware remap (b&7 = XCD); z=4 splits; reg-staged T14; T5 setprio on MFMA.
__global__ __launch_bounds__(256, 2) void k_flash(
    const bf16* __restrict__ Qb, const bf16* __restrict__ Kb, const bf16* __restrict__ Vt,
    float* __restrict__ Opart, float2* __restrict__ MLpart) {
    int b = blockIdx.x;
    int cx = b & 7, jj = b >> 3;
    int p = cx + 8 * (jj >> 3);
    int qb = jj & 7;
    int h = p & 15, z = p >> 4;
    int q0 = qb * 128;
    int t = threadIdx.x;
    int lane = t & 63, wq = t >> 6;
    int l31 = lane & 31, hi = lane >> 5;
    __shared__ bf16 Kl[64 * 128];
    __shared__ bf16 Vl[128 * 64];
    const bf16* Kh = Kb + (size_t)h * 1048576;
    const bf16* Vh = Vt + (size_t)h * 1048576;
    int q = q0 + wq * 32 + l31;
    bf16x8 qf[8];
#pragma unroll
    for (int db = 0; db < 8; db++)
        qf[db] = *(const bf16x8*)&Qb[(size_t)h * 131072 + (size_t)q * 128 + db * 16 + hi * 8];
    f32x16 o[4] = {};
    float mm = -1e30f, ll = 0.f;
    int krow = t >> 4;
    int kcol = (t & 15) * 8;
    int kdst = krow * 128 + (((t & 15) ^ (krow & 7)) * 8);
    int vrow = t >> 3;
    int vcol = (t & 7) * 8;
    int vdst = vrow * 64 + (((t & 7) ^ (vrow & 7)) * 8);
    int swr = (l31 & 7) << 3;
    int it0 = z * 32, it1 = it0 + 32;
    bf16x8 kst[4], vst[4];
    {
        int s0 = it0 * 64;
#pragma unroll
        for (int j = 0; j < 4; j++)
            kst[j] = *(const bf16x8*)&Kh[(size_t)(s0 + krow + 16 * j) * 128 + kcol];
#pragma unroll
        for (int j = 0; j < 4; j++)
            vst[j] = *(const bf16x8*)&Vh[(size_t)(vrow + 32 * j) * 8192 + s0 + vcol];
    }
    for (int it = it0; it < it1; ++it) {
        __syncthreads();
#pragma unroll
        for (int j = 0; j < 4; j++) *(bf16x8*)&Kl[kdst + j * 2048] = kst[j];
#pragma unroll
        for (int j = 0; j < 4; j++) *(bf16x8*)&Vl[vdst + j * 2048] = vst[j];
        __syncthreads();
        if (it + 1 < it1) {
            int s1 = (it + 1) * 64;
#pragma unroll
            for (int j = 0; j < 4; j++)
                kst[j] = *(const bf16x8*)&Kh[(size_t)(s1 + krow + 16 * j) * 128 + kcol];
#pragma unroll
            for (int j = 0; j < 4; j++)
                vst[j] = *(const bf16x8*)&Vh[(size_t)(vrow + 32 * j) * 8192 + s1 + vcol];
        }
        // QK^T swapped
        f32x16 sA = {}, sB = {};
        __builtin_amdgcn_s_setprio(1);
#pragma unroll
        for (int db = 0; db < 8; db++) {
            int doff = (db * 16 + hi * 8) ^ swr;
            bf16x8 ka = *(const bf16x8*)&Kl[l31 * 128 + doff];
            bf16x8 kb = *(const bf16x8*)&Kl[(32 + l31) * 128 + doff];
            sA = MFMA32(ka, qf[db], sA);
            sB = MFMA32(kb, qf[db], sB);
        }
        __builtin_amdgcn_s_setprio(0);
        // in-register softmax (base-2), defer-max
        float tm = -1e30f;
#pragma unroll
        for (int r = 0; r < 16; r++) { tm = fmaxf(tm, sA[r]); tm = fmaxf(tm, sB[r]); }
        tm = fmaxf(tm, __shfl_xor(tm, 32));
        if (__any(tm > mm + 11.5416f)) {
            float mn = fmaxf(mm, tm);
            float al = exp2f(mm - mn);
#pragma unroll
            for (int dt = 0; dt < 4; dt++)
#pragma unroll
                for (int r = 0; r < 16; r++) o[dt][r] *= al;
            ll *= al; mm = mn;
        }
        float ps = 0.f;
#pragma unroll
        for (int r = 0; r < 16; r++) { sA[r] = exp2f(sA[r] - mm); ps += sA[r]; }
#pragma unroll
        for (int r = 0; r < 16; r++) { sB[r] = exp2f(sB[r] - mm); ps += sB[r]; }
        ll += ps + __shfl_xor(ps, 32);
        unsigned int w0[8], w1[8];
#pragma unroll
        for (int qd = 0; qd < 4; qd++) {
            w0[qd * 2]     = pkbf(sA[qd * 4], sA[qd * 4 + 1]);
            w0[qd * 2 + 1] = pkbf(sA[qd * 4 + 2], sA[qd * 4 + 3]);
            w1[qd * 2]     = pkbf(sB[qd * 4], sB[qd * 4 + 1]);
            w1[qd * 2 + 1] = pkbf(sB[qd * 4 + 2], sB[qd * 4 + 3]);
        }
        // PV: O^T += V^T x P^T
#pragma unroll
        for (int ks = 0; ks < 4; ks++) {
            const int a4 = (ks & 1) * 4;
            unsigned int oo0, oo1, ss0, ss1;
            if ((ks >> 1) == 0) {
                oo0 = hi ? w0[a4 + 2] : w0[a4];
                oo1 = hi ? w0[a4 + 3] : w0[a4 + 1];
                ss0 = hi ? w0[a4] : w0[a4 + 2];
                ss1 = hi ? w0[a4 + 1] : w0[a4 + 3];
            } else {
                oo0 = hi ? w1[a4 + 2] : w1[a4];
                oo1 = hi ? w1[a4 + 3] : w1[a4 + 1];
                ss0 = hi ? w1[a4] : w1[a4 + 2];
                ss1 = hi ? w1[a4 + 1] : w1[a4 + 3];
            }
            unsigned int x0 = (unsigned int)__shfl_xor((int)ss0, 32);
            unsigned int x1 = (unsigned int)__shfl_xor((int)ss1, 32);
            union { unsigned int w[4]; bf16x8 v; } fr;
            fr.w[0] = hi ? x0 : oo0;
            fr.w[1] = hi ? x1 : oo1;
            fr.w[2] = hi ? oo0 : x0;
            fr.w[3] = hi ? oo1 : x1;
            __builtin_amdgcn_s_setprio(1);
#pragma unroll
            for (int dt = 0; dt < 4; dt++) {
                int e = (dt * 32 + l31) * 64 + ((ks * 16 + hi * 8) ^ swr);
                bf16x8 vf = *(const bf16x8*)&Vl[e];
                o[dt] = MFMA32(vf, fr.v, o[dt]);
            }
            __builtin_amdgcn_s_setprio(0);
        }
    }
    // permuted, per-lane-contiguous epilogue: lane owns 256B (4 full lines)
    size_t obase = ((size_t)(z * 16 + h) * 1024 + q) * 128 + hi * 64;
#pragma unroll
    for (int dt = 0; dt < 4; dt++) {
#pragma unroll
        for (int c = 0; c < 4; c++) {
            float4 f = make_float4(o[dt][4 * c], o[dt][4 * c + 1],
                                   o[dt][4 * c + 2], o[dt][4 * c + 3]);
            *(float4*)&Opart[obase + dt * 16 + c * 4] = f;
        }
    }
    if (hi == 0) MLpart[(size_t)(z * 16 + h) * 1024 + q] = make_float2(mm, ll);
}

// ---------------- combine 4 partials -> Ob bf16 [q][h*128+d] ----------------
// Opart p-index: p = hi*64 + dt*16 + c*4 + j  <->  d = dt*32 + 8c + 4hi + j.
__global__ __launch_bounds__(256) void k_combine(
    const float* __restrict__ Opart, const float2* __restrict__ MLpart,
    bf16* __restrict__ Ob) {
    int q = blockIdx.x, t = threadIdx.x;
    int h = t >> 4, pb = (t & 15) * 8;
    int hi = pb >> 6, dt = (pb >> 4) & 3, c = (pb >> 2) & 3;
    int da = dt * 32 + 8 * c + 4 * hi;
    int db = dt * 32 + 8 * (c + 1) + 4 * hi;
    float m[4], l[4];
#pragma unroll
    for (int z = 0; z < 4; z++) {
        float2 v = MLpart[(size_t)(z * 16 + h) * 1024 + q];
        m[z] = v.x; l[z] = v.y;
    }
    float M = -1e30f;
#pragma unroll
    for (int z = 0; z < 4; z++) M = fmaxf(M, m[z]);
    float e[4], den = 0.f;
#pragma unroll
    for (int z = 0; z < 4; z++) { e[z] = exp2f(m[z] - M); den += e[z] * l[z]; }
    float inv = 1.0f / den;
    float acc[8] = {};
#pragma unroll
    for (int z = 0; z < 4; z++) {
        const float4* p = (const float4*)&Opart[((size_t)(z * 16 + h) * 1024 + q) * 128 + pb];
        float4 a = p[0], b2 = p[1];
        float s = e[z] * inv;
        acc[0] += a.x * s; acc[1] += a.y * s; acc[2] += a.z * s; acc[3] += a.w * s;
        acc[4] += b2.x * s; acc[5] += b2.y * s; acc[6] += b2.z * s; acc[7] += b2.w * s;
    }
    bf16x4 oa, ob;
#pragma unroll
    for (int j = 0; j < 4; j++) { oa[j] = (bf16)acc[j]; ob[j] = (bf16)acc[4 + j]; }
    *(bf16x4*)&Ob[(size_t)q * 2048 + h * 128 + da] = oa;
    *(bf16x4*)&Ob[(size_t)q * 2048 + h * 128 + db] = ob;
}

extern "C" void kernel_launch(void* const* d_in, const int* in_sizes, int n_in,
                              void* d_out, int out_size, void* d_ws, size_t ws_size,
                              hipStream_t stream) {
    const float* x       = (const float*)d_in[0];
    const float* cache_k = (const float*)d_in[1];
    const float* cache_v = (const float*)d_in[2];
    const float* theta   = (const float*)d_in[5];
    const float* Wq = (const float*)d_in[6];
    const float* bq = (const float*)d_in[7];
    const float* Wk = (const float*)d_in[8];
    const float* bk = (const float*)d_in[9];
    const float* Wv = (const float*)d_in[10];
    const float* bv = (const float*)d_in[11];
    const float* Wo = (const float*)d_in[12];
    const float* bo = (const float*)d_in[13];
    const float* gq = (const float*)d_in[14];
    const float* gk = (const float*)d_in[15];
    float* out = (float*)d_out;

    // ws layout (132 MB). WoT placed before WqT so WqT..qraw (32MB) is a
    // contiguous dead region at flash time -> Opart overlay.
    bf16* xbf = (bf16*)d_ws;                 // 4 MB; dead after QKV gemm -> MLpart
    bf16* WoT = xbf + 2097152;               // 8 MB (alive until final gemm)
    bf16* WqT = WoT + 4194304;               // 8 MB
    bf16* WkT = WqT + 4194304;
    bf16* WvT = WkT + 4194304;
    float* qraw = (float*)(WvT + 4194304);   // 8 MB each
    float* kraw = qraw + 2097152;
    float* vraw = kraw + 2097152;
    bf16* Qb = (bf16*)(vraw + 2097152);      // [16][1024][128]
    bf16* Kb = Qb + 2097152;                 // [16][8192][128]
    bf16* Vt = Kb + 16777216;                // [16][128][8192]
    bf16* Ob = Vt + 16777216;                // [1024][2048]

    float* Opart = (float*)WqT;              // [4][16][1024][128] fp32 = 32 MB
    float2* MLpart = (float2*)xbf;           // [4][16][1024] float2 = 512 KB

    k_prep<<<5120, 256, 0, stream>>>(x, xbf, Wq, Wk, Wv, Wo, WqT, WkT, WvT, WoT);
    k_gemm<<<dim3(16, 16, 3), 256, 0, stream>>>(xbf, WqT, WkT, WvT, bq, bk, bv, qraw, kraw, vraw);
    k_post<<<10240, 256, 0, stream>>>(qraw, kraw, vraw, cache_k, cache_v, gq, gk, theta, Qb, Kb, Vt);
    k_flash<<<512, 256, 0, stream>>>(Qb, Kb, Vt, Opart, MLpart);
    k_combine<<<1024, 256, 0, stream>>>(Opart, MLpart, Ob);
    k_gemm<<<dim3(16, 16, 1), 256, 0, stream>>>(Ob, WoT, WoT, WoT, bo, bo, bo, out, out, out);
}